// Round 7
// baseline (1993.778 us; speedup 1.0000x reference)
//
#include <hip/hip_runtime.h>

#define NN 50000
#define EE 1000000
#define HALF 25000

__device__ __forceinline__ float wsum(float v){
#pragma unroll
  for(int m=1;m<64;m<<=1) v += __shfl_xor(v,m,64);
  return v;
}

__global__ __launch_bounds__(256) void zero_k(int* counts, int* cursor){
  int i = blockIdx.x*blockDim.x + threadIdx.x;
  if(i < NN){ counts[i] = 0; cursor[i] = 0; }
}

__global__ __launch_bounds__(256) void node_mlp(const float* __restrict__ X, const float* __restrict__ w,
                                                const float* __restrict__ b, const float* __restrict__ g,
                                                const float* __restrict__ beta, float* __restrict__ x){
  int wid  = (blockIdx.x*blockDim.x + threadIdx.x) >> 6;
  int lane = threadIdx.x & 63;
  if(wid >= NN) return;
  float acc = b[lane];
#pragma unroll
  for(int k=0;k<16;k++) acc += X[wid*16+k] * w[k*64+lane];
  float mu  = wsum(acc) * (1.0f/64.0f);
  float d   = acc - mu;
  float var = wsum(d*d) * (1.0f/64.0f);
  float y   = d * rsqrtf(var + 1e-5f) * g[lane] + beta[lane];
  x[(size_t)wid*64 + lane] = fmaxf(y, 0.0f);
}

__global__ __launch_bounds__(256) void hist_k(const int* __restrict__ src, int* __restrict__ counts){
  int e = blockIdx.x*blockDim.x + threadIdx.x;
  if(e < EE){
    int s = src[e];
    if((unsigned)s >= NN) s = 0;
    atomicAdd(&counts[s], 1);
  }
}

__global__ __launch_bounds__(256) void scan1_k(const int* __restrict__ counts, int* __restrict__ bsum){
  int i = blockIdx.x*256 + threadIdx.x;
  int v = (i < NN) ? counts[i] : 0;
  int s = v;
#pragma unroll
  for(int m=1;m<64;m<<=1) s += __shfl_xor(s,m,64);
  __shared__ int sm[4];
  if((threadIdx.x & 63) == 0) sm[threadIdx.x>>6] = s;
  __syncthreads();
  if(threadIdx.x == 0) bsum[blockIdx.x] = sm[0]+sm[1]+sm[2]+sm[3];
}

__global__ __launch_bounds__(256) void scan2_k(const int* __restrict__ bsum, int* __restrict__ bpre,
                                               int* __restrict__ offs){
  const int NB = (NN + 255)/256;
  int t = threadIdx.x;
  __shared__ int sm[256];
  int v = (t < NB) ? bsum[t] : 0;
  sm[t] = v; __syncthreads();
  for(int off=1; off<256; off<<=1){
    int u = (t >= off) ? sm[t-off] : 0;
    __syncthreads();
    sm[t] += u;
    __syncthreads();
  }
  if(t < NB) bpre[t] = sm[t] - v;
  if(t == 0) offs[NN] = EE;
}

__global__ __launch_bounds__(256) void scan3_k(const int* __restrict__ counts, const int* __restrict__ bpre,
                                               int* __restrict__ offs){
  int i = blockIdx.x*256 + threadIdx.x;
  int t = threadIdx.x;
  __shared__ int sm[256];
  int v = (i < NN) ? counts[i] : 0;
  sm[t] = v; __syncthreads();
  for(int off=1; off<256; off<<=1){
    int u = (t >= off) ? sm[t-off] : 0;
    __syncthreads();
    sm[t] += u;
    __syncthreads();
  }
  if(i < NN) offs[i] = bpre[blockIdx.x] + sm[t] - v;
}

__global__ __launch_bounds__(256) void scatter_k(const int* __restrict__ src, const int* __restrict__ offs,
                                                 int* __restrict__ cursor, int* __restrict__ perm){
  int e = blockIdx.x*blockDim.x + threadIdx.x;
  if(e < EE){
    int s = src[e];
    if((unsigned)s >= NN) s = 0;
    int pos = offs[s] + atomicAdd(&cursor[s], 1);
    perm[pos] = e;
  }
}

__global__ __launch_bounds__(256) void prep_k(const int* __restrict__ perm, const int* __restrict__ tgt,
                                              int* __restrict__ tgt_s){
  int i = blockIdx.x*blockDim.x + threadIdx.x;
  if(i < EE){
    int t = tgt[perm[i]];
    if((unsigned)t >= NN) t = 0;
    tgt_s[i] = t;
  }
}

__global__ __launch_bounds__(256) void edge_mlp_q(const int* __restrict__ perm, const float* __restrict__ ea,
                                                  const float* __restrict__ w, const float* __restrict__ b,
                                                  const float* __restrict__ g, const float* __restrict__ beta,
                                                  const float* __restrict__ gat_a, const float* __restrict__ out_a,
                                                  float* __restrict__ q8, float* __restrict__ q_out){
  int i = blockIdx.x*blockDim.x + threadIdx.x;
  if(i >= EE) return;
  int pe = perm[i];
  float in[8];
#pragma unroll
  for(int k=0;k<8;k++) in[k] = ea[(size_t)pe*8 + k];
  float y[64];
#pragma unroll
  for(int j=0;j<64;j++){
    float acc = b[j];
#pragma unroll
    for(int k=0;k<8;k++) acc += in[k] * w[k*64+j];
    y[j] = acc;
  }
  float mu = 0.f;
#pragma unroll
  for(int j=0;j<64;j++) mu += y[j];
  mu *= (1.0f/64.0f);
  float var = 0.f;
#pragma unroll
  for(int j=0;j<64;j++){ float d = y[j]-mu; var += d*d; }
  var *= (1.0f/64.0f);
  float inv = rsqrtf(var + 1e-5f);
#pragma unroll
  for(int j=0;j<64;j++) y[j] = fmaxf((y[j]-mu)*inv*g[j] + beta[j], 0.0f);
#pragma unroll
  for(int r=0;r<8;r++){
    const float* av = gat_a + r*192 + 128;
    float d = 0.f;
#pragma unroll
    for(int j=0;j<64;j++) d += y[j]*av[j];
    q8[(size_t)i*8 + r] = d;
  }
  {
    const float* av = out_a + 128;
    float d = 0.f;
#pragma unroll
    for(int j=0;j<64;j++) d += y[j]*av[j];
    q_out[i] = d;
  }
}

__global__ __launch_bounds__(64) void cvec_k(const float* __restrict__ gat_W, const float* __restrict__ gat_a,
                                             float* __restrict__ cdir){
  int h = blockIdx.x, k = threadIdx.x;
  const float* W = gat_W + (size_t)h*64*64;
  const float* a = gat_a + (size_t)h*192;
  float cs = 0.f, ct = 0.f;
#pragma unroll
  for(int j=0;j<64;j++){ float wv = W[k*64+j]; cs += wv*a[j]; ct += wv*a[64+j]; }
  cdir[h*64 + k]       = cs;
  cdir[512 + h*64 + k] = ct;
}

__global__ __launch_bounds__(256) void pq_k(const float* __restrict__ x, const float* __restrict__ cdir,
                                            float* __restrict__ ps8, float* __restrict__ pt8){
  int wid  = (blockIdx.x*blockDim.x + threadIdx.x) >> 6;
  int lane = threadIdx.x & 63;
  if(wid >= NN) return;
  float xv = x[(size_t)wid*64 + lane];
#pragma unroll 1
  for(int h=0;h<8;h++){
    float a = wsum(xv * cdir[h*64+lane]);
    float c = wsum(xv * cdir[512 + h*64+lane]);
    if(lane == 0){ ps8[wid*8+h] = a; pt8[wid*8+h] = c; }
  }
}

__global__ __launch_bounds__(256) void agg_k(const int* __restrict__ offs, const int* __restrict__ tgt_s,
    const float* __restrict__ ps8, const float* __restrict__ pt8, const float* __restrict__ q8,
    const float* __restrict__ x, float* __restrict__ pre, int nbase){
  int wid  = nbase + ((blockIdx.x*blockDim.x + threadIdx.x) >> 6);
  int lane = threadIdx.x & 63;
  int quad = lane >> 4, l16 = lane & 15;
  int b  = offs[wid];
  int e2 = offs[wid+1];
  float ps[8];
#pragma unroll
  for(int h=0;h<8;h++) ps[h] = ps8[wid*8+h];
  float m[8];
#pragma unroll
  for(int h=0;h<8;h++) m[h] = -3.0e38f;
  for(int i=b+quad; i<e2; i+=4){
    int t = tgt_s[i];
    const float4* qp = (const float4*)(q8 + (size_t)i*8);
    const float4* pp = (const float4*)(pt8 + (size_t)t*8);
    float4 qa = qp[0], qb = qp[1], pa = pp[0], pb = pp[1];
    float sv[8] = {qa.x+pa.x, qa.y+pa.y, qa.z+pa.z, qa.w+pa.w,
                   qb.x+pb.x, qb.y+pb.y, qb.z+pb.z, qb.w+pb.w};
#pragma unroll
    for(int h=0;h<8;h++){
      float s = ps[h] + sv[h];
      s = (s > 0.f) ? s : 0.01f*s;
      m[h] = fmaxf(m[h], s);
    }
  }
#pragma unroll
  for(int h=0;h<8;h++){
    m[h] = fmaxf(m[h], __shfl_xor(m[h],16,64));
    m[h] = fmaxf(m[h], __shfl_xor(m[h],32,64));
  }
  float  den[8];
  float4 num[8];
#pragma unroll
  for(int h=0;h<8;h++){ den[h] = 0.f; num[h] = make_float4(0.f,0.f,0.f,0.f); }
  const float4* X4 = (const float4*)x;
  for(int i=b+quad; i<e2; i+=4){
    int t = tgt_s[i];
    const float4* qp = (const float4*)(q8 + (size_t)i*8);
    const float4* pp = (const float4*)(pt8 + (size_t)t*8);
    float4 qa = qp[0], qb = qp[1], pa = pp[0], pb = pp[1];
    float4 xv = X4[(size_t)t*16 + l16];
    float sv[8] = {qa.x+pa.x, qa.y+pa.y, qa.z+pa.z, qa.w+pa.w,
                   qb.x+pb.x, qb.y+pb.y, qb.z+pb.z, qb.w+pb.w};
#pragma unroll
    for(int h=0;h<8;h++){
      float s = ps[h] + sv[h];
      s = (s > 0.f) ? s : 0.01f*s;
      float w = __expf(s - m[h]);
      den[h]   += w;
      num[h].x += w*xv.x; num[h].y += w*xv.y; num[h].z += w*xv.z; num[h].w += w*xv.w;
    }
  }
#pragma unroll
  for(int h=0;h<8;h++){
    den[h]   += __shfl_xor(den[h],16,64);   den[h]   += __shfl_xor(den[h],32,64);
    num[h].x += __shfl_xor(num[h].x,16,64); num[h].x += __shfl_xor(num[h].x,32,64);
    num[h].y += __shfl_xor(num[h].y,16,64); num[h].y += __shfl_xor(num[h].y,32,64);
    num[h].z += __shfl_xor(num[h].z,16,64); num[h].z += __shfl_xor(num[h].z,32,64);
    num[h].w += __shfl_xor(num[h].w,16,64); num[h].w += __shfl_xor(num[h].w,32,64);
  }
  float* dst = pre + (size_t)(wid - nbase)*512;
#pragma unroll
  for(int k=0;k<2;k++){
    int h = 2*quad + k;
    float invd = (den[h] > 0.f) ? 1.0f/den[h] : 0.f;
    float4 o = make_float4(num[h].x*invd, num[h].y*invd, num[h].z*invd, num[h].w*invd);
    ((float4*)(dst + h*64))[l16] = o;
  }
}

// ---- transform: lane=node; W/OW rows wave-uniform (scalar loads); v tiled to 16 cols;
//      ALL local arrays constant-indexed (no scratch demotion). heads 4g..4g+3 -> part g ----
__global__ __launch_bounds__(64) void transform_k(const float* __restrict__ pre,
                                                  const float* __restrict__ gat_W,
                                                  const float* __restrict__ outW,
                                                  float* __restrict__ h2part,   // [2][NN][64], part = blockIdx.y
                                                  int nbase, int cn){
  __shared__ float plds[64*65];
  int g    = blockIdx.y;
  int n0   = blockIdx.x * 64;
  int lane = threadIdx.x;
  h2part += (size_t)g * NN * 64;
  float outacc[64];
#pragma unroll
  for(int c=0;c<64;c++) outacc[c] = 0.f;
#pragma unroll 1
  for(int hh=0; hh<4; hh++){
    int h = g*4 + hh;
    __syncthreads();
#pragma unroll 1
    for(int r=0;r<64;r++){
      int n = n0 + r;
      plds[r*65 + lane] = (n < cn) ? pre[(size_t)n*512 + h*64 + lane] : 0.f;
    }
    __syncthreads();
    const float* W  = gat_W + (size_t)h*4096;
    const float* OW = outW  + (size_t)h*4096;
#pragma unroll 1
    for(int cc=0; cc<4; cc++){
      float v[16];
#pragma unroll
      for(int c=0;c<16;c++) v[c] = 0.f;
#pragma unroll 1
      for(int j=0;j<64;j++){
        float pj = plds[lane*65 + j];
        const float* Wr = W + j*64 + cc*16;   // wave-uniform -> s_load
#pragma unroll
        for(int c=0;c<16;c++) v[c] = fmaf(Wr[c], pj, v[c]);
      }
#pragma unroll
      for(int c=0;c<16;c++){                   // FULLY unrolled: v/outacc stay in VGPRs
        float z  = (v[c] > 0.f) ? v[c] : expm1f(v[c]);
        float z2 = (z    > 0.f) ? z    : expm1f(z);
        const float* OWr = OW + (cc*16+c)*64;  // wave-uniform -> s_load
#pragma unroll
        for(int c2=0;c2<64;c2++) outacc[c2] = fmaf(OWr[c2], z2, outacc[c2]);
      }
    }
  }
  int nloc = n0 + lane;
  if(nloc < cn){
    float4* dst = (float4*)(h2part + (size_t)(nbase + nloc)*64);
#pragma unroll
    for(int k=0;k<16;k++) dst[k] = make_float4(outacc[4*k], outacc[4*k+1], outacc[4*k+2], outacc[4*k+3]);
  }
}

__global__ __launch_bounds__(256) void finalize2_k(const float* __restrict__ p0, const float* __restrict__ p1,
                                                   const float* __restrict__ out_a, float* __restrict__ h2f,
                                                   float* __restrict__ ps_o, float* __restrict__ pt_o){
  int wid  = (blockIdx.x*blockDim.x + threadIdx.x) >> 6;
  int lane = threadIdx.x & 63;
  if(wid >= NN) return;
  float v = p0[(size_t)wid*64 + lane] + p1[(size_t)wid*64 + lane];
  float ps = wsum(v * out_a[lane]);
  float pt = wsum(v * out_a[64+lane]);
  if(lane == 0){ ps_o[wid] = ps; pt_o[wid] = pt; }
  h2f[(size_t)wid*64 + lane] = v;
}

__global__ __launch_bounds__(256) void agg_out(const int* __restrict__ offs, const int* __restrict__ tgt_s,
                                               const float* __restrict__ ps_o, const float* __restrict__ pt_o,
                                               const float* __restrict__ q_out, const float* __restrict__ h2f,
                                               float* __restrict__ dout){
  int wid  = (blockIdx.x*blockDim.x + threadIdx.x) >> 6;
  int lane = threadIdx.x & 63;
  if(wid >= NN) return;
  int quad = lane >> 4, l16 = lane & 15;
  int b  = offs[wid];
  int e2 = offs[wid+1];
  float ps = ps_o[wid];
  float m = -3.0e38f;
  for(int i=b+quad; i<e2; i+=4){
    float s = ps + pt_o[tgt_s[i]] + q_out[i];
    s = (s > 0.f) ? s : 0.01f*s;
    m = fmaxf(m, s);
  }
  m = fmaxf(m, __shfl_xor(m,16,64));
  m = fmaxf(m, __shfl_xor(m,32,64));
  const float4* H4 = (const float4*)h2f;
  float4 num = make_float4(0.f,0.f,0.f,0.f);
  float den = 0.f;
  for(int i=b+quad; i<e2; i+=4){
    int t = tgt_s[i];
    float s = ps + pt_o[t] + q_out[i];
    s = (s > 0.f) ? s : 0.01f*s;
    float w = __expf(s - m);
    den += w;
    float4 hv = H4[(size_t)t*16 + l16];
    num.x += w*hv.x; num.y += w*hv.y; num.z += w*hv.z; num.w += w*hv.w;
  }
  den   += __shfl_xor(den,16,64);   den   += __shfl_xor(den,32,64);
  num.x += __shfl_xor(num.x,16,64); num.x += __shfl_xor(num.x,32,64);
  num.y += __shfl_xor(num.y,16,64); num.y += __shfl_xor(num.y,32,64);
  num.z += __shfl_xor(num.z,16,64); num.z += __shfl_xor(num.z,32,64);
  num.w += __shfl_xor(num.w,16,64); num.w += __shfl_xor(num.w,32,64);
  float inv = (den > 0.f) ? 1.0f/den : 0.f;
  float z[4];
  float mloc = -3.0e38f;
#pragma unroll
  for(int k=0;k<4;k++){
    float hp = ((&num.x)[k]) * inv;
    z[k] = (hp > 0.f) ? hp : expm1f(hp);
    mloc = fmaxf(mloc, z[k]);
  }
#pragma unroll
  for(int msk=1; msk<16; msk<<=1) mloc = fmaxf(mloc, __shfl_xor(mloc,msk,64));
  float ssum = 0.f;
#pragma unroll
  for(int k=0;k<4;k++) ssum += __expf(z[k] - mloc);
#pragma unroll
  for(int msk=1; msk<16; msk<<=1) ssum += __shfl_xor(ssum,msk,64);
  float lse = mloc + logf(ssum);
  if(quad == 0){
    float4 o = make_float4(z[0]-lse, z[1]-lse, z[2]-lse, z[3]-lse);
    ((float4*)dout)[(size_t)wid*16 + l16] = o;
  }
}

extern "C" void kernel_launch(void* const* d_in, const int* in_sizes, int n_in,
                              void* d_out, int out_size, void* d_ws, size_t ws_size,
                              hipStream_t stream) {
  const float* X         = (const float*)d_in[0];
  const float* edge_attr = (const float*)d_in[1];
  const int*   edge_index= (const int*)d_in[2];
  const float* w_node    = (const float*)d_in[4];
  const float* b_node    = (const float*)d_in[5];
  const float* g_node    = (const float*)d_in[6];
  const float* beta_node = (const float*)d_in[7];
  const float* w_edge    = (const float*)d_in[8];
  const float* b_edge    = (const float*)d_in[9];
  const float* g_edge    = (const float*)d_in[10];
  const float* beta_edge = (const float*)d_in[11];
  const float* gat_W     = (const float*)d_in[12];
  const float* gat_a     = (const float*)d_in[13];
  const float* out_W     = (const float*)d_in[14];
  const float* out_a     = (const float*)d_in[15];
  float* dout = (float*)d_out;

  const int* src = edge_index;
  const int* tgt = edge_index + EE;

  char* base = (char*)d_ws;
  size_t off = 0;
  auto take = [&](size_t bytes)->char*{ char* p = base + off; off += (bytes + 31) & ~(size_t)31; return p; };
  int*    counts = (int*)  take((size_t)NN*4);
  int*    cursor = (int*)  take((size_t)NN*4);
  int*    offs   = (int*)  take((size_t)(NN+1)*4);
  int*    bsum   = (int*)  take(256*4);
  int*    bpre   = (int*)  take(256*4);
  float*  ps_o   = (float*)take((size_t)NN*4);
  float*  pt_o   = (float*)take((size_t)NN*4);
  float*  cdir   = (float*)take(1024*4);
  int*    perm   = (int*)  take((size_t)EE*4);
  int*    tgt_s  = (int*)  take((size_t)EE*4);
  float*  ps8    = (float*)take((size_t)NN*8*4);
  float*  pt8    = (float*)take((size_t)NN*8*4);
  float*  x      = (float*)take((size_t)NN*64*4);
  float*  h2p    = (float*)take((size_t)2*NN*64*4);  // [2][NN][64] contiguous
  float*  q8     = (float*)take((size_t)EE*8*4);     // dead after agg_k passes
  float*  q_out  = (float*)take((size_t)EE*4);
  float*  pre    = (float*)take((size_t)HALF*512*4);
  float*  h2f    = q8;   // alias into dead q8

  const int NBLK_N  = (NN*64 + 255)/256;
  const int NBLK_E  = (EE + 255)/256;
  const int NBLK_S  = (NN + 255)/256;
  const int NBLK_A  = HALF/4;
  const int NBLK_T  = (HALF + 63)/64;

  zero_k   <<<NBLK_S, 256, 0, stream>>>(counts, cursor);
  node_mlp <<<NBLK_N, 256, 0, stream>>>(X, w_node, b_node, g_node, beta_node, x);
  hist_k   <<<NBLK_E, 256, 0, stream>>>(src, counts);
  scan1_k  <<<NBLK_S, 256, 0, stream>>>(counts, bsum);
  scan2_k  <<<1,      256, 0, stream>>>(bsum, bpre, offs);
  scan3_k  <<<NBLK_S, 256, 0, stream>>>(counts, bpre, offs);
  scatter_k<<<NBLK_E, 256, 0, stream>>>(src, offs, cursor, perm);
  prep_k   <<<NBLK_E, 256, 0, stream>>>(perm, tgt, tgt_s);
  edge_mlp_q<<<NBLK_E,256, 0, stream>>>(perm, edge_attr, w_edge, b_edge, g_edge, beta_edge,
                                        gat_a, out_a, q8, q_out);
  cvec_k   <<<8,       64, 0, stream>>>(gat_W, gat_a, cdir);
  pq_k     <<<NBLK_N, 256, 0, stream>>>(x, cdir, ps8, pt8);

  for(int half=0; half<2; half++){
    int nbase = half*HALF;
    agg_k<<<NBLK_A, 256, 0, stream>>>(offs, tgt_s, ps8, pt8, q8, x, pre, nbase);
    dim3 tg((unsigned)NBLK_T, 2);
    transform_k<<<tg, 64, 0, stream>>>(pre, gat_W, out_W, h2p, nbase, HALF);
  }

  finalize2_k<<<NBLK_N, 256, 0, stream>>>(h2p, h2p + (size_t)NN*64, out_a, h2f, ps_o, pt_o);
  agg_out   <<<NBLK_N, 256, 0, stream>>>(offs, tgt_s, ps_o, pt_o, q_out, h2f, dout);
}

// Round 8
// 936.118 us; speedup vs baseline: 2.1298x; 2.1298x over previous
//
#include <hip/hip_runtime.h>

#define NN 50000
#define EE 1000000
#define HALF 25000

__device__ __forceinline__ float wsum(float v){
#pragma unroll
  for(int m=1;m<64;m<<=1) v += __shfl_xor(v,m,64);
  return v;
}

__global__ __launch_bounds__(256) void zero_k(int* counts, int* cursor){
  int i = blockIdx.x*blockDim.x + threadIdx.x;
  if(i < NN){ counts[i] = 0; cursor[i] = 0; }
}

__global__ __launch_bounds__(256) void node_mlp(const float* __restrict__ X, const float* __restrict__ w,
                                                const float* __restrict__ b, const float* __restrict__ g,
                                                const float* __restrict__ beta, float* __restrict__ x){
  int wid  = (blockIdx.x*blockDim.x + threadIdx.x) >> 6;
  int lane = threadIdx.x & 63;
  if(wid >= NN) return;
  float acc = b[lane];
#pragma unroll
  for(int k=0;k<16;k++) acc += X[wid*16+k] * w[k*64+lane];
  float mu  = wsum(acc) * (1.0f/64.0f);
  float d   = acc - mu;
  float var = wsum(d*d) * (1.0f/64.0f);
  float y   = d * rsqrtf(var + 1e-5f) * g[lane] + beta[lane];
  x[(size_t)wid*64 + lane] = fmaxf(y, 0.0f);
}

__global__ __launch_bounds__(256) void hist_k(const int* __restrict__ src, int* __restrict__ counts){
  int e = blockIdx.x*blockDim.x + threadIdx.x;
  if(e < EE){
    int s = src[e];
    if((unsigned)s >= NN) s = 0;
    atomicAdd(&counts[s], 1);
  }
}

__global__ __launch_bounds__(256) void scan1_k(const int* __restrict__ counts, int* __restrict__ bsum){
  int i = blockIdx.x*256 + threadIdx.x;
  int v = (i < NN) ? counts[i] : 0;
  int s = v;
#pragma unroll
  for(int m=1;m<64;m<<=1) s += __shfl_xor(s,m,64);
  __shared__ int sm[4];
  if((threadIdx.x & 63) == 0) sm[threadIdx.x>>6] = s;
  __syncthreads();
  if(threadIdx.x == 0) bsum[blockIdx.x] = sm[0]+sm[1]+sm[2]+sm[3];
}

__global__ __launch_bounds__(256) void scan2_k(const int* __restrict__ bsum, int* __restrict__ bpre,
                                               int* __restrict__ offs){
  const int NB = (NN + 255)/256;
  int t = threadIdx.x;
  __shared__ int sm[256];
  int v = (t < NB) ? bsum[t] : 0;
  sm[t] = v; __syncthreads();
  for(int off=1; off<256; off<<=1){
    int u = (t >= off) ? sm[t-off] : 0;
    __syncthreads();
    sm[t] += u;
    __syncthreads();
  }
  if(t < NB) bpre[t] = sm[t] - v;
  if(t == 0) offs[NN] = EE;
}

__global__ __launch_bounds__(256) void scan3_k(const int* __restrict__ counts, const int* __restrict__ bpre,
                                               int* __restrict__ offs){
  int i = blockIdx.x*256 + threadIdx.x;
  int t = threadIdx.x;
  __shared__ int sm[256];
  int v = (i < NN) ? counts[i] : 0;
  sm[t] = v; __syncthreads();
  for(int off=1; off<256; off<<=1){
    int u = (t >= off) ? sm[t-off] : 0;
    __syncthreads();
    sm[t] += u;
    __syncthreads();
  }
  if(i < NN) offs[i] = bpre[blockIdx.x] + sm[t] - v;
}

__global__ __launch_bounds__(256) void scatter_k(const int* __restrict__ src, const int* __restrict__ offs,
                                                 int* __restrict__ cursor, int* __restrict__ perm){
  int e = blockIdx.x*blockDim.x + threadIdx.x;
  if(e < EE){
    int s = src[e];
    if((unsigned)s >= NN) s = 0;
    int pos = offs[s] + atomicAdd(&cursor[s], 1);
    perm[pos] = e;
  }
}

__global__ __launch_bounds__(256) void prep_k(const int* __restrict__ perm, const int* __restrict__ tgt,
                                              int* __restrict__ tgt_s){
  int i = blockIdx.x*blockDim.x + threadIdx.x;
  if(i < EE){
    int t = tgt[perm[i]];
    if((unsigned)t >= NN) t = 0;
    tgt_s[i] = t;
  }
}

__global__ __launch_bounds__(256) void edge_mlp_q(const int* __restrict__ perm, const float* __restrict__ ea,
                                                  const float* __restrict__ w, const float* __restrict__ b,
                                                  const float* __restrict__ g, const float* __restrict__ beta,
                                                  const float* __restrict__ gat_a, const float* __restrict__ out_a,
                                                  float* __restrict__ q8, float* __restrict__ q_out){
  int i = blockIdx.x*blockDim.x + threadIdx.x;
  if(i >= EE) return;
  int pe = perm[i];
  float in[8];
#pragma unroll
  for(int k=0;k<8;k++) in[k] = ea[(size_t)pe*8 + k];
  float y[64];
#pragma unroll
  for(int j=0;j<64;j++){
    float acc = b[j];
#pragma unroll
    for(int k=0;k<8;k++) acc += in[k] * w[k*64+j];
    y[j] = acc;
  }
  float mu = 0.f;
#pragma unroll
  for(int j=0;j<64;j++) mu += y[j];
  mu *= (1.0f/64.0f);
  float var = 0.f;
#pragma unroll
  for(int j=0;j<64;j++){ float d = y[j]-mu; var += d*d; }
  var *= (1.0f/64.0f);
  float inv = rsqrtf(var + 1e-5f);
#pragma unroll
  for(int j=0;j<64;j++) y[j] = fmaxf((y[j]-mu)*inv*g[j] + beta[j], 0.0f);
#pragma unroll
  for(int r=0;r<8;r++){
    const float* av = gat_a + r*192 + 128;
    float d = 0.f;
#pragma unroll
    for(int j=0;j<64;j++) d += y[j]*av[j];
    q8[(size_t)i*8 + r] = d;
  }
  {
    const float* av = out_a + 128;
    float d = 0.f;
#pragma unroll
    for(int j=0;j<64;j++) d += y[j]*av[j];
    q_out[i] = d;
  }
}

__global__ __launch_bounds__(64) void cvec_k(const float* __restrict__ gat_W, const float* __restrict__ gat_a,
                                             float* __restrict__ cdir){
  int h = blockIdx.x, k = threadIdx.x;
  const float* W = gat_W + (size_t)h*64*64;
  const float* a = gat_a + (size_t)h*192;
  float cs = 0.f, ct = 0.f;
#pragma unroll
  for(int j=0;j<64;j++){ float wv = W[k*64+j]; cs += wv*a[j]; ct += wv*a[64+j]; }
  cdir[h*64 + k]       = cs;
  cdir[512 + h*64 + k] = ct;
}

__global__ __launch_bounds__(256) void pq_k(const float* __restrict__ x, const float* __restrict__ cdir,
                                            float* __restrict__ ps8, float* __restrict__ pt8){
  int wid  = (blockIdx.x*blockDim.x + threadIdx.x) >> 6;
  int lane = threadIdx.x & 63;
  if(wid >= NN) return;
  float xv = x[(size_t)wid*64 + lane];
#pragma unroll 1
  for(int h=0;h<8;h++){
    float a = wsum(xv * cdir[h*64+lane]);
    float c = wsum(xv * cdir[512 + h*64+lane]);
    if(lane == 0){ ps8[wid*8+h] = a; pt8[wid*8+h] = c; }
  }
}

__global__ __launch_bounds__(256) void agg_k(const int* __restrict__ offs, const int* __restrict__ tgt_s,
    const float* __restrict__ ps8, const float* __restrict__ pt8, const float* __restrict__ q8,
    const float* __restrict__ x, float* __restrict__ pre, int nbase){
  int wid  = nbase + ((blockIdx.x*blockDim.x + threadIdx.x) >> 6);
  int lane = threadIdx.x & 63;
  int quad = lane >> 4, l16 = lane & 15;
  int b  = offs[wid];
  int e2 = offs[wid+1];
  float ps[8];
#pragma unroll
  for(int h=0;h<8;h++) ps[h] = ps8[wid*8+h];
  float m[8];
#pragma unroll
  for(int h=0;h<8;h++) m[h] = -3.0e38f;
  for(int i=b+quad; i<e2; i+=4){
    int t = tgt_s[i];
    const float4* qp = (const float4*)(q8 + (size_t)i*8);
    const float4* pp = (const float4*)(pt8 + (size_t)t*8);
    float4 qa = qp[0], qb = qp[1], pa = pp[0], pb = pp[1];
    float sv[8] = {qa.x+pa.x, qa.y+pa.y, qa.z+pa.z, qa.w+pa.w,
                   qb.x+pb.x, qb.y+pb.y, qb.z+pb.z, qb.w+pb.w};
#pragma unroll
    for(int h=0;h<8;h++){
      float s = ps[h] + sv[h];
      s = (s > 0.f) ? s : 0.01f*s;
      m[h] = fmaxf(m[h], s);
    }
  }
#pragma unroll
  for(int h=0;h<8;h++){
    m[h] = fmaxf(m[h], __shfl_xor(m[h],16,64));
    m[h] = fmaxf(m[h], __shfl_xor(m[h],32,64));
  }
  float  den[8];
  float4 num[8];
#pragma unroll
  for(int h=0;h<8;h++){ den[h] = 0.f; num[h] = make_float4(0.f,0.f,0.f,0.f); }
  const float4* X4 = (const float4*)x;
  for(int i=b+quad; i<e2; i+=4){
    int t = tgt_s[i];
    const float4* qp = (const float4*)(q8 + (size_t)i*8);
    const float4* pp = (const float4*)(pt8 + (size_t)t*8);
    float4 qa = qp[0], qb = qp[1], pa = pp[0], pb = pp[1];
    float4 xv = X4[(size_t)t*16 + l16];
    float sv[8] = {qa.x+pa.x, qa.y+pa.y, qa.z+pa.z, qa.w+pa.w,
                   qb.x+pb.x, qb.y+pb.y, qb.z+pb.z, qb.w+pb.w};
#pragma unroll
    for(int h=0;h<8;h++){
      float s = ps[h] + sv[h];
      s = (s > 0.f) ? s : 0.01f*s;
      float w = __expf(s - m[h]);
      den[h]   += w;
      num[h].x += w*xv.x; num[h].y += w*xv.y; num[h].z += w*xv.z; num[h].w += w*xv.w;
    }
  }
#pragma unroll
  for(int h=0;h<8;h++){
    den[h]   += __shfl_xor(den[h],16,64);   den[h]   += __shfl_xor(den[h],32,64);
    num[h].x += __shfl_xor(num[h].x,16,64); num[h].x += __shfl_xor(num[h].x,32,64);
    num[h].y += __shfl_xor(num[h].y,16,64); num[h].y += __shfl_xor(num[h].y,32,64);
    num[h].z += __shfl_xor(num[h].z,16,64); num[h].z += __shfl_xor(num[h].z,32,64);
    num[h].w += __shfl_xor(num[h].w,16,64); num[h].w += __shfl_xor(num[h].w,32,64);
  }
  float* dst = pre + (size_t)(wid - nbase)*512;
#pragma unroll
  for(int k=0;k<2;k++){
    int h = 2*quad + k;
    float invd = (den[h] > 0.f) ? 1.0f/den[h] : 0.f;
    float4 o = make_float4(num[h].x*invd, num[h].y*invd, num[h].z*invd, num[h].w*invd);
    ((float4*)(dst + h*64))[l16] = o;
  }
}

// ---- transform v3: LDS-tiled GEMM. Block = 256 thr / 64 nodes; 8 heads sequential.
// Per head: stage pre-tile (transposed, pad 68) + W_h + OW_h in LDS; 4x4 register tile
// per thread (2 ds_read_b128 per 16 FMA). Epilogue: h2f + shfl-reduced ps_o/pt_o. ----
__global__ __launch_bounds__(256) void transform_k(const float* __restrict__ pre,
                                                   const float* __restrict__ gat_W,
                                                   const float* __restrict__ outW,
                                                   const float* __restrict__ out_a,
                                                   float* __restrict__ h2f,
                                                   float* __restrict__ ps_o,
                                                   float* __restrict__ pt_o,
                                                   int nbase, int cn){
  __shared__ float pz[64*68];   // pre_t [j][n] / z_t [c][n], pad 68 keeps b128 aligned
  __shared__ float Wl[4096];
  __shared__ float Ol[4096];
  int tid = threadIdx.x;
  int n0  = blockIdx.x * 64;
  int a   = tid >> 4;           // node group 0..15 (nodes a*4..a*4+3)
  int b   = tid & 15;           // col group  0..15 (cols  b*4..b*4+3)
  float outacc[16];
#pragma unroll
  for(int i=0;i<16;i++) outacc[i] = 0.f;

#pragma unroll 1
  for(int h=0; h<8; h++){
    __syncthreads();   // previous head's matvec2 done reading pz/Ol
    // stage pre_t (transposed), W_h, OW_h
#pragma unroll 1
    for(int r=0;r<16;r++){
      int flat = r*256 + tid;
      int n = flat >> 6, j = flat & 63;
      int gn = n0 + n;
      pz[j*68 + n] = (gn < cn) ? pre[(size_t)gn*512 + h*64 + j] : 0.f;
      Wl[flat] = gat_W[(size_t)h*4096 + flat];
      Ol[flat] = outW [(size_t)h*4096 + flat];
    }
    __syncthreads();
    // matvec1: v = pre_h @ W_h  (4 nodes x 4 cols per thread)
    float v[16];
#pragma unroll
    for(int i=0;i<16;i++) v[i] = 0.f;
#pragma unroll 4
    for(int j=0;j<64;j++){
      float4 pn = *(const float4*)&pz[j*68 + a*4];
      float4 wc = *(const float4*)&Wl[j*64 + b*4];
#pragma unroll
      for(int na=0;na<4;na++){
        float pv = (&pn.x)[na];
        v[na*4+0] = fmaf(pv, wc.x, v[na*4+0]);
        v[na*4+1] = fmaf(pv, wc.y, v[na*4+1]);
        v[na*4+2] = fmaf(pv, wc.z, v[na*4+2]);
        v[na*4+3] = fmaf(pv, wc.w, v[na*4+3]);
      }
    }
    __syncthreads();   // matvec1 readers done before z overwrites pz
    // double-ELU, write z_t[c][n]
#pragma unroll
    for(int cb=0;cb<4;cb++){
      float4 z4;
#pragma unroll
      for(int na=0;na<4;na++){
        float z  = (v[na*4+cb] > 0.f) ? v[na*4+cb] : expm1f(v[na*4+cb]);
        float z2 = (z > 0.f) ? z : expm1f(z);
        (&z4.x)[na] = z2;
      }
      *(float4*)&pz[(b*4+cb)*68 + a*4] = z4;
    }
    __syncthreads();
    // matvec2: outacc += z2 @ OW_h
#pragma unroll 4
    for(int c=0;c<64;c++){
      float4 zn = *(const float4*)&pz[c*68 + a*4];
      float4 oc = *(const float4*)&Ol[c*64 + b*4];
#pragma unroll
      for(int na=0;na<4;na++){
        float zv = (&zn.x)[na];
        outacc[na*4+0] = fmaf(zv, oc.x, outacc[na*4+0]);
        outacc[na*4+1] = fmaf(zv, oc.y, outacc[na*4+1]);
        outacc[na*4+2] = fmaf(zv, oc.z, outacc[na*4+2]);
        outacc[na*4+3] = fmaf(zv, oc.w, outacc[na*4+3]);
      }
    }
  }
  // epilogue: h2f store + fused ps_o/pt_o (reduce over the 16 col-groups = 16 lanes)
  float oas[4], oat[4];
#pragma unroll
  for(int cb=0;cb<4;cb++){ oas[cb] = out_a[b*4+cb]; oat[cb] = out_a[64 + b*4+cb]; }
#pragma unroll
  for(int na=0;na<4;na++){
    int nl = n0 + a*4 + na;
    float4 o = make_float4(outacc[na*4+0], outacc[na*4+1], outacc[na*4+2], outacc[na*4+3]);
    float sp = o.x*oas[0] + o.y*oas[1] + o.z*oas[2] + o.w*oas[3];
    float st = o.x*oat[0] + o.y*oat[1] + o.z*oat[2] + o.w*oat[3];
#pragma unroll
    for(int msk=1; msk<16; msk<<=1){
      sp += __shfl_xor(sp, msk, 64);
      st += __shfl_xor(st, msk, 64);
    }
    if(nl < cn){
      *(float4*)&h2f[(size_t)(nbase + nl)*64 + b*4] = o;
      if(b == 0){ ps_o[nbase + nl] = sp; pt_o[nbase + nl] = st; }
    }
  }
}

__global__ __launch_bounds__(256) void agg_out(const int* __restrict__ offs, const int* __restrict__ tgt_s,
                                               const float* __restrict__ ps_o, const float* __restrict__ pt_o,
                                               const float* __restrict__ q_out, const float* __restrict__ h2f,
                                               float* __restrict__ dout){
  int wid  = (blockIdx.x*blockDim.x + threadIdx.x) >> 6;
  int lane = threadIdx.x & 63;
  if(wid >= NN) return;
  int quad = lane >> 4, l16 = lane & 15;
  int b  = offs[wid];
  int e2 = offs[wid+1];
  float ps = ps_o[wid];
  float m = -3.0e38f;
  for(int i=b+quad; i<e2; i+=4){
    float s = ps + pt_o[tgt_s[i]] + q_out[i];
    s = (s > 0.f) ? s : 0.01f*s;
    m = fmaxf(m, s);
  }
  m = fmaxf(m, __shfl_xor(m,16,64));
  m = fmaxf(m, __shfl_xor(m,32,64));
  const float4* H4 = (const float4*)h2f;
  float4 num = make_float4(0.f,0.f,0.f,0.f);
  float den = 0.f;
  for(int i=b+quad; i<e2; i+=4){
    int t = tgt_s[i];
    float s = ps + pt_o[t] + q_out[i];
    s = (s > 0.f) ? s : 0.01f*s;
    float w = __expf(s - m);
    den += w;
    float4 hv = H4[(size_t)t*16 + l16];
    num.x += w*hv.x; num.y += w*hv.y; num.z += w*hv.z; num.w += w*hv.w;
  }
  den   += __shfl_xor(den,16,64);   den   += __shfl_xor(den,32,64);
  num.x += __shfl_xor(num.x,16,64); num.x += __shfl_xor(num.x,32,64);
  num.y += __shfl_xor(num.y,16,64); num.y += __shfl_xor(num.y,32,64);
  num.z += __shfl_xor(num.z,16,64); num.z += __shfl_xor(num.z,32,64);
  num.w += __shfl_xor(num.w,16,64); num.w += __shfl_xor(num.w,32,64);
  float inv = (den > 0.f) ? 1.0f/den : 0.f;
  float z[4];
  float mloc = -3.0e38f;
#pragma unroll
  for(int k=0;k<4;k++){
    float hp = ((&num.x)[k]) * inv;
    z[k] = (hp > 0.f) ? hp : expm1f(hp);
    mloc = fmaxf(mloc, z[k]);
  }
#pragma unroll
  for(int msk=1; msk<16; msk<<=1) mloc = fmaxf(mloc, __shfl_xor(mloc,msk,64));
  float ssum = 0.f;
#pragma unroll
  for(int k=0;k<4;k++) ssum += __expf(z[k] - mloc);
#pragma unroll
  for(int msk=1; msk<16; msk<<=1) ssum += __shfl_xor(ssum,msk,64);
  float lse = mloc + logf(ssum);
  if(quad == 0){
    float4 o = make_float4(z[0]-lse, z[1]-lse, z[2]-lse, z[3]-lse);
    ((float4*)dout)[(size_t)wid*16 + l16] = o;
  }
}

extern "C" void kernel_launch(void* const* d_in, const int* in_sizes, int n_in,
                              void* d_out, int out_size, void* d_ws, size_t ws_size,
                              hipStream_t stream) {
  const float* X         = (const float*)d_in[0];
  const float* edge_attr = (const float*)d_in[1];
  const int*   edge_index= (const int*)d_in[2];
  const float* w_node    = (const float*)d_in[4];
  const float* b_node    = (const float*)d_in[5];
  const float* g_node    = (const float*)d_in[6];
  const float* beta_node = (const float*)d_in[7];
  const float* w_edge    = (const float*)d_in[8];
  const float* b_edge    = (const float*)d_in[9];
  const float* g_edge    = (const float*)d_in[10];
  const float* beta_edge = (const float*)d_in[11];
  const float* gat_W     = (const float*)d_in[12];
  const float* gat_a     = (const float*)d_in[13];
  const float* out_W     = (const float*)d_in[14];
  const float* out_a     = (const float*)d_in[15];
  float* dout = (float*)d_out;

  const int* src = edge_index;
  const int* tgt = edge_index + EE;

  char* base = (char*)d_ws;
  size_t off = 0;
  auto take = [&](size_t bytes)->char*{ char* p = base + off; off += (bytes + 31) & ~(size_t)31; return p; };
  int*    counts = (int*)  take((size_t)NN*4);
  int*    cursor = (int*)  take((size_t)NN*4);
  int*    offs   = (int*)  take((size_t)(NN+1)*4);
  int*    bsum   = (int*)  take(256*4);
  int*    bpre   = (int*)  take(256*4);
  float*  ps_o   = (float*)take((size_t)NN*4);
  float*  pt_o   = (float*)take((size_t)NN*4);
  float*  cdir   = (float*)take(1024*4);
  int*    perm   = (int*)  take((size_t)EE*4);
  int*    tgt_s  = (int*)  take((size_t)EE*4);
  float*  ps8    = (float*)take((size_t)NN*8*4);
  float*  pt8    = (float*)take((size_t)NN*8*4);
  float*  x      = (float*)take((size_t)NN*64*4);
  float*  h2f    = (float*)take((size_t)NN*64*4);
  float*  q8     = (float*)take((size_t)EE*8*4);
  float*  q_out  = (float*)take((size_t)EE*4);
  float*  pre    = (float*)take((size_t)HALF*512*4);
  // total ~125 MB

  const int NBLK_N  = (NN*64 + 255)/256;
  const int NBLK_E  = (EE + 255)/256;
  const int NBLK_S  = (NN + 255)/256;
  const int NBLK_A  = HALF/4;              // agg_k: 4 nodes per 256-thr block
  const int NBLK_T  = (HALF + 63)/64;      // transform: 64 nodes per block -> 391

  zero_k   <<<NBLK_S, 256, 0, stream>>>(counts, cursor);
  node_mlp <<<NBLK_N, 256, 0, stream>>>(X, w_node, b_node, g_node, beta_node, x);
  hist_k   <<<NBLK_E, 256, 0, stream>>>(src, counts);
  scan1_k  <<<NBLK_S, 256, 0, stream>>>(counts, bsum);
  scan2_k  <<<1,      256, 0, stream>>>(bsum, bpre, offs);
  scan3_k  <<<NBLK_S, 256, 0, stream>>>(counts, bpre, offs);
  scatter_k<<<NBLK_E, 256, 0, stream>>>(src, offs, cursor, perm);
  prep_k   <<<NBLK_E, 256, 0, stream>>>(perm, tgt, tgt_s);
  edge_mlp_q<<<NBLK_E,256, 0, stream>>>(perm, edge_attr, w_edge, b_edge, g_edge, beta_edge,
                                        gat_a, out_a, q8, q_out);
  cvec_k   <<<8,       64, 0, stream>>>(gat_W, gat_a, cdir);
  pq_k     <<<NBLK_N, 256, 0, stream>>>(x, cdir, ps8, pt8);

  for(int half=0; half<2; half++){
    int nbase = half*HALF;
    agg_k      <<<NBLK_A, 256, 0, stream>>>(offs, tgt_s, ps8, pt8, q8, x, pre, nbase);
    transform_k<<<NBLK_T, 256, 0, stream>>>(pre, gat_W, out_W, out_a, h2f, ps_o, pt_o, nbase, HALF);
  }

  agg_out<<<NBLK_N, 256, 0, stream>>>(offs, tgt_s, ps_o, pt_o, q_out, h2f, dout);
}

// Round 9
// 929.167 us; speedup vs baseline: 2.1458x; 1.0075x over previous
//
#include <hip/hip_runtime.h>

#define NN 50000
#define EE 1000000
#define HALF 25000

__device__ __forceinline__ float wsum(float v){
#pragma unroll
  for(int m=1;m<64;m<<=1) v += __shfl_xor(v,m,64);
  return v;
}
// order-preserving float<->uint for atomicMax
__device__ __forceinline__ unsigned encf(float f){
  unsigned u = __float_as_uint(f);
  return (u & 0x80000000u) ? ~u : (u | 0x80000000u);
}
__device__ __forceinline__ float decf(unsigned u){
  u = (u & 0x80000000u) ? (u & 0x7fffffffu) : ~u;
  return __uint_as_float(u);
}

__global__ __launch_bounds__(256) void zero_k(int* counts, int* cursor, unsigned* mx){
  int i = blockIdx.x*blockDim.x + threadIdx.x;
  if(i < NN){ counts[i] = 0; cursor[i] = 0; }
  if(i < 64) mx[i] = 0u;
}

__global__ __launch_bounds__(256) void node_mlp(const float* __restrict__ X, const float* __restrict__ w,
                                                const float* __restrict__ b, const float* __restrict__ g,
                                                const float* __restrict__ beta, float* __restrict__ x){
  int wid  = (blockIdx.x*blockDim.x + threadIdx.x) >> 6;
  int lane = threadIdx.x & 63;
  if(wid >= NN) return;
  float acc = b[lane];
#pragma unroll
  for(int k=0;k<16;k++) acc += X[wid*16+k] * w[k*64+lane];
  float mu  = wsum(acc) * (1.0f/64.0f);
  float d   = acc - mu;
  float var = wsum(d*d) * (1.0f/64.0f);
  float y   = d * rsqrtf(var + 1e-5f) * g[lane] + beta[lane];
  x[(size_t)wid*64 + lane] = fmaxf(y, 0.0f);
}

__global__ __launch_bounds__(256) void hist_k(const int* __restrict__ src, int* __restrict__ counts){
  int e = blockIdx.x*blockDim.x + threadIdx.x;
  if(e < EE){
    int s = src[e];
    if((unsigned)s >= NN) s = 0;
    atomicAdd(&counts[s], 1);
  }
}

__global__ __launch_bounds__(256) void scan1_k(const int* __restrict__ counts, int* __restrict__ bsum){
  int i = blockIdx.x*256 + threadIdx.x;
  int v = (i < NN) ? counts[i] : 0;
  int s = v;
#pragma unroll
  for(int m=1;m<64;m<<=1) s += __shfl_xor(s,m,64);
  __shared__ int sm[4];
  if((threadIdx.x & 63) == 0) sm[threadIdx.x>>6] = s;
  __syncthreads();
  if(threadIdx.x == 0) bsum[blockIdx.x] = sm[0]+sm[1]+sm[2]+sm[3];
}

__global__ __launch_bounds__(256) void scan2_k(const int* __restrict__ bsum, int* __restrict__ bpre,
                                               int* __restrict__ offs){
  const int NB = (NN + 255)/256;
  int t = threadIdx.x;
  __shared__ int sm[256];
  int v = (t < NB) ? bsum[t] : 0;
  sm[t] = v; __syncthreads();
  for(int off=1; off<256; off<<=1){
    int u = (t >= off) ? sm[t-off] : 0;
    __syncthreads();
    sm[t] += u;
    __syncthreads();
  }
  if(t < NB) bpre[t] = sm[t] - v;
  if(t == 0) offs[NN] = EE;
}

__global__ __launch_bounds__(256) void scan3_k(const int* __restrict__ counts, const int* __restrict__ bpre,
                                               int* __restrict__ offs){
  int i = blockIdx.x*256 + threadIdx.x;
  int t = threadIdx.x;
  __shared__ int sm[256];
  int v = (i < NN) ? counts[i] : 0;
  sm[t] = v; __syncthreads();
  for(int off=1; off<256; off<<=1){
    int u = (t >= off) ? sm[t-off] : 0;
    __syncthreads();
    sm[t] += u;
    __syncthreads();
  }
  if(i < NN) offs[i] = bpre[blockIdx.x] + sm[t] - v;
}

// fused: rank[e] = CSR position; tgt_s[pos] = tgt[e]  (perm/prep eliminated)
__global__ __launch_bounds__(256) void scatter_k(const int* __restrict__ src, const int* __restrict__ tgt,
                                                 const int* __restrict__ offs, int* __restrict__ cursor,
                                                 int* __restrict__ rank, int* __restrict__ tgt_s){
  int e = blockIdx.x*blockDim.x + threadIdx.x;
  if(e < EE){
    int s = src[e];
    if((unsigned)s >= NN) s = 0;
    int pos = offs[s] + atomicAdd(&cursor[s], 1);
    rank[e] = pos;
    int t = tgt[e];
    if((unsigned)t >= NN) t = 0;
    tgt_s[pos] = t;
  }
}

// coalesced ea reads (natural edge order), scattered q writes via rank
__global__ __launch_bounds__(256) void edge_mlp_q(const int* __restrict__ rank, const float* __restrict__ ea,
                                                  const float* __restrict__ w, const float* __restrict__ b,
                                                  const float* __restrict__ g, const float* __restrict__ beta,
                                                  const float* __restrict__ gat_a, const float* __restrict__ out_a,
                                                  float* __restrict__ q8, float* __restrict__ q_out){
  int e = blockIdx.x*blockDim.x + threadIdx.x;
  if(e >= EE) return;
  float4 ia = ((const float4*)ea)[(size_t)e*2];
  float4 ib = ((const float4*)ea)[(size_t)e*2+1];
  float in[8] = {ia.x, ia.y, ia.z, ia.w, ib.x, ib.y, ib.z, ib.w};
  float y[64];
#pragma unroll
  for(int j=0;j<64;j++){
    float acc = b[j];
#pragma unroll
    for(int k=0;k<8;k++) acc += in[k] * w[k*64+j];
    y[j] = acc;
  }
  float mu = 0.f;
#pragma unroll
  for(int j=0;j<64;j++) mu += y[j];
  mu *= (1.0f/64.0f);
  float var = 0.f;
#pragma unroll
  for(int j=0;j<64;j++){ float d = y[j]-mu; var += d*d; }
  var *= (1.0f/64.0f);
  float inv = rsqrtf(var + 1e-5f);
#pragma unroll
  for(int j=0;j<64;j++) y[j] = fmaxf((y[j]-mu)*inv*g[j] + beta[j], 0.0f);
  int r = rank[e];
  float qv[8];
#pragma unroll
  for(int rr=0;rr<8;rr++){
    const float* av = gat_a + rr*192 + 128;
    float d = 0.f;
#pragma unroll
    for(int j=0;j<64;j++) d += y[j]*av[j];
    qv[rr] = d;
  }
  ((float4*)q8)[(size_t)r*2]   = make_float4(qv[0],qv[1],qv[2],qv[3]);
  ((float4*)q8)[(size_t)r*2+1] = make_float4(qv[4],qv[5],qv[6],qv[7]);
  {
    const float* av = out_a + 128;
    float d = 0.f;
#pragma unroll
    for(int j=0;j<64;j++) d += y[j]*av[j];
    q_out[r] = d;
  }
}

// per-head max over q8 columns + q_out -> mx[0..8]
__global__ __launch_bounds__(256) void maxq_k(const float* __restrict__ q8, const float* __restrict__ q_out,
                                              unsigned* __restrict__ mx){
  float m[9];
#pragma unroll
  for(int r=0;r<9;r++) m[r] = -3.0e38f;
  for(int i = blockIdx.x*256 + threadIdx.x; i < EE; i += gridDim.x*256){
    float4 a = ((const float4*)q8)[(size_t)i*2];
    float4 c = ((const float4*)q8)[(size_t)i*2+1];
    m[0]=fmaxf(m[0],a.x); m[1]=fmaxf(m[1],a.y); m[2]=fmaxf(m[2],a.z); m[3]=fmaxf(m[3],a.w);
    m[4]=fmaxf(m[4],c.x); m[5]=fmaxf(m[5],c.y); m[6]=fmaxf(m[6],c.z); m[7]=fmaxf(m[7],c.w);
    m[8]=fmaxf(m[8], q_out[i]);
  }
#pragma unroll
  for(int r=0;r<9;r++)
#pragma unroll
    for(int msk=1;msk<64;msk<<=1) m[r] = fmaxf(m[r], __shfl_xor(m[r],msk,64));
  __shared__ float sm[4][9];
  int wv = threadIdx.x>>6, lane = threadIdx.x&63;
  if(lane == 0){
#pragma unroll
    for(int r=0;r<9;r++) sm[wv][r] = m[r];
  }
  __syncthreads();
  if(threadIdx.x < 9){
    int r = threadIdx.x;
    float v = fmaxf(fmaxf(sm[0][r],sm[1][r]), fmaxf(sm[2][r],sm[3][r]));
    atomicMax(&mx[r], encf(v));
  }
}

// per-head max over ps8/pt8 -> mx[16..23], mx[24..31]
__global__ __launch_bounds__(256) void maxp_k(const float* __restrict__ ps8, const float* __restrict__ pt8,
                                              unsigned* __restrict__ mx){
  float m[16];
#pragma unroll
  for(int r=0;r<16;r++) m[r] = -3.0e38f;
  for(int i = blockIdx.x*256 + threadIdx.x; i < NN; i += gridDim.x*256){
    float4 a = ((const float4*)ps8)[(size_t)i*2];
    float4 c = ((const float4*)ps8)[(size_t)i*2+1];
    float4 d = ((const float4*)pt8)[(size_t)i*2];
    float4 e = ((const float4*)pt8)[(size_t)i*2+1];
    m[0]=fmaxf(m[0],a.x); m[1]=fmaxf(m[1],a.y); m[2]=fmaxf(m[2],a.z); m[3]=fmaxf(m[3],a.w);
    m[4]=fmaxf(m[4],c.x); m[5]=fmaxf(m[5],c.y); m[6]=fmaxf(m[6],c.z); m[7]=fmaxf(m[7],c.w);
    m[8]=fmaxf(m[8],d.x); m[9]=fmaxf(m[9],d.y); m[10]=fmaxf(m[10],d.z); m[11]=fmaxf(m[11],d.w);
    m[12]=fmaxf(m[12],e.x); m[13]=fmaxf(m[13],e.y); m[14]=fmaxf(m[14],e.z); m[15]=fmaxf(m[15],e.w);
  }
#pragma unroll
  for(int r=0;r<16;r++)
#pragma unroll
    for(int msk=1;msk<64;msk<<=1) m[r] = fmaxf(m[r], __shfl_xor(m[r],msk,64));
  __shared__ float sm[4][16];
  int wv = threadIdx.x>>6, lane = threadIdx.x&63;
  if(lane == 0){
#pragma unroll
    for(int r=0;r<16;r++) sm[wv][r] = m[r];
  }
  __syncthreads();
  if(threadIdx.x < 16){
    int r = threadIdx.x;
    float v = fmaxf(fmaxf(sm[0][r],sm[1][r]), fmaxf(sm[2][r],sm[3][r]));
    atomicMax(&mx[16+r], encf(v));
  }
}

// max over ps_o/pt_o -> mx[32], mx[33]
__global__ __launch_bounds__(256) void maxpo_k(const float* __restrict__ ps_o, const float* __restrict__ pt_o,
                                               unsigned* __restrict__ mx){
  float m0 = -3.0e38f, m1 = -3.0e38f;
  for(int i = blockIdx.x*256 + threadIdx.x; i < NN; i += gridDim.x*256){
    m0 = fmaxf(m0, ps_o[i]); m1 = fmaxf(m1, pt_o[i]);
  }
#pragma unroll
  for(int msk=1;msk<64;msk<<=1){ m0=fmaxf(m0,__shfl_xor(m0,msk,64)); m1=fmaxf(m1,__shfl_xor(m1,msk,64)); }
  __shared__ float sm[4][2];
  int wv = threadIdx.x>>6, lane = threadIdx.x&63;
  if(lane == 0){ sm[wv][0]=m0; sm[wv][1]=m1; }
  __syncthreads();
  if(threadIdx.x < 2){
    int r = threadIdx.x;
    float v = fmaxf(fmaxf(sm[0][r],sm[1][r]), fmaxf(sm[2][r],sm[3][r]));
    atomicMax(&mx[32+r], encf(v));
  }
}

__global__ __launch_bounds__(64) void cvec_k(const float* __restrict__ gat_W, const float* __restrict__ gat_a,
                                             float* __restrict__ cdir){
  int h = blockIdx.x, k = threadIdx.x;
  const float* W = gat_W + (size_t)h*64*64;
  const float* a = gat_a + (size_t)h*192;
  float cs = 0.f, ct = 0.f;
#pragma unroll
  for(int j=0;j<64;j++){ float wv = W[k*64+j]; cs += wv*a[j]; ct += wv*a[64+j]; }
  cdir[h*64 + k]       = cs;
  cdir[512 + h*64 + k] = ct;
}

__global__ __launch_bounds__(256) void pq_k(const float* __restrict__ x, const float* __restrict__ cdir,
                                            float* __restrict__ ps8, float* __restrict__ pt8){
  int wid  = (blockIdx.x*blockDim.x + threadIdx.x) >> 6;
  int lane = threadIdx.x & 63;
  if(wid >= NN) return;
  float xv = x[(size_t)wid*64 + lane];
#pragma unroll 1
  for(int h=0;h<8;h++){
    float a = wsum(xv * cdir[h*64+lane]);
    float c = wsum(xv * cdir[512 + h*64+lane]);
    if(lane == 0){ ps8[wid*8+h] = a; pt8[wid*8+h] = c; }
  }
}

// SINGLE-PASS aggregation using upper-bound max M_h (softmax shift-invariance)
__global__ __launch_bounds__(256) void agg_k(const int* __restrict__ offs, const int* __restrict__ tgt_s,
    const float* __restrict__ ps8, const float* __restrict__ pt8, const float* __restrict__ q8,
    const float* __restrict__ x, const unsigned* __restrict__ mx, float* __restrict__ pre, int nbase){
  int wid  = nbase + ((blockIdx.x*blockDim.x + threadIdx.x) >> 6);
  int lane = threadIdx.x & 63;
  int quad = lane >> 4, l16 = lane & 15;
  int b  = offs[wid];
  int e2 = offs[wid+1];
  float ps[8], M[8];
#pragma unroll
  for(int h=0;h<8;h++){
    ps[h] = ps8[wid*8+h];
    float B = decf(mx[h]) + decf(mx[16+h]) + decf(mx[24+h]);
    M[h] = (B > 0.f) ? B : 0.01f*B;   // lrelu(bound) >= lrelu(s) for all s
  }
  float  den[8];
  float4 num[8];
#pragma unroll
  for(int h=0;h<8;h++){ den[h] = 0.f; num[h] = make_float4(0.f,0.f,0.f,0.f); }
  const float4* X4 = (const float4*)x;
  for(int i=b+quad; i<e2; i+=4){
    int t = tgt_s[i];
    float4 qa = ((const float4*)q8)[(size_t)i*2];
    float4 qb = ((const float4*)q8)[(size_t)i*2+1];
    float4 pa = ((const float4*)pt8)[(size_t)t*2];
    float4 pb = ((const float4*)pt8)[(size_t)t*2+1];
    float4 xv = X4[(size_t)t*16 + l16];
    float sv[8] = {qa.x+pa.x, qa.y+pa.y, qa.z+pa.z, qa.w+pa.w,
                   qb.x+pb.x, qb.y+pb.y, qb.z+pb.z, qb.w+pb.w};
#pragma unroll
    for(int h=0;h<8;h++){
      float s = ps[h] + sv[h];
      s = (s > 0.f) ? s : 0.01f*s;
      float w = __expf(s - M[h]);
      den[h]   += w;
      num[h].x += w*xv.x; num[h].y += w*xv.y; num[h].z += w*xv.z; num[h].w += w*xv.w;
    }
  }
#pragma unroll
  for(int h=0;h<8;h++){
    den[h]   += __shfl_xor(den[h],16,64);   den[h]   += __shfl_xor(den[h],32,64);
    num[h].x += __shfl_xor(num[h].x,16,64); num[h].x += __shfl_xor(num[h].x,32,64);
    num[h].y += __shfl_xor(num[h].y,16,64); num[h].y += __shfl_xor(num[h].y,32,64);
    num[h].z += __shfl_xor(num[h].z,16,64); num[h].z += __shfl_xor(num[h].z,32,64);
    num[h].w += __shfl_xor(num[h].w,16,64); num[h].w += __shfl_xor(num[h].w,32,64);
  }
  float* dst = pre + (size_t)(wid - nbase)*512;
#pragma unroll
  for(int k=0;k<2;k++){
    int h = 2*quad + k;
    float invd = (den[h] > 0.f) ? 1.0f/den[h] : 0.f;
    float4 o = make_float4(num[h].x*invd, num[h].y*invd, num[h].z*invd, num[h].w*invd);
    ((float4*)(dst + h*64))[l16] = o;
  }
}

// transform v3 (unchanged from R8): LDS-tiled GEMM, epilogue h2f + ps_o/pt_o
__global__ __launch_bounds__(256) void transform_k(const float* __restrict__ pre,
                                                   const float* __restrict__ gat_W,
                                                   const float* __restrict__ outW,
                                                   const float* __restrict__ out_a,
                                                   float* __restrict__ h2f,
                                                   float* __restrict__ ps_o,
                                                   float* __restrict__ pt_o,
                                                   int nbase, int cn){
  __shared__ float pz[64*68];
  __shared__ float Wl[4096];
  __shared__ float Ol[4096];
  int tid = threadIdx.x;
  int n0  = blockIdx.x * 64;
  int a   = tid >> 4;
  int b   = tid & 15;
  float outacc[16];
#pragma unroll
  for(int i=0;i<16;i++) outacc[i] = 0.f;
#pragma unroll 1
  for(int h=0; h<8; h++){
    __syncthreads();
#pragma unroll 1
    for(int r=0;r<16;r++){
      int flat = r*256 + tid;
      int n = flat >> 6, j = flat & 63;
      int gn = n0 + n;
      pz[j*68 + n] = (gn < cn) ? pre[(size_t)gn*512 + h*64 + j] : 0.f;
      Wl[flat] = gat_W[(size_t)h*4096 + flat];
      Ol[flat] = outW [(size_t)h*4096 + flat];
    }
    __syncthreads();
    float v[16];
#pragma unroll
    for(int i=0;i<16;i++) v[i] = 0.f;
#pragma unroll 4
    for(int j=0;j<64;j++){
      float4 pn = *(const float4*)&pz[j*68 + a*4];
      float4 wc = *(const float4*)&Wl[j*64 + b*4];
#pragma unroll
      for(int na=0;na<4;na++){
        float pv = (&pn.x)[na];
        v[na*4+0] = fmaf(pv, wc.x, v[na*4+0]);
        v[na*4+1] = fmaf(pv, wc.y, v[na*4+1]);
        v[na*4+2] = fmaf(pv, wc.z, v[na*4+2]);
        v[na*4+3] = fmaf(pv, wc.w, v[na*4+3]);
      }
    }
    __syncthreads();
#pragma unroll
    for(int cb=0;cb<4;cb++){
      float4 z4;
#pragma unroll
      for(int na=0;na<4;na++){
        float z  = (v[na*4+cb] > 0.f) ? v[na*4+cb] : expm1f(v[na*4+cb]);
        float z2 = (z > 0.f) ? z : expm1f(z);
        (&z4.x)[na] = z2;
      }
      *(float4*)&pz[(b*4+cb)*68 + a*4] = z4;
    }
    __syncthreads();
#pragma unroll 4
    for(int c=0;c<64;c++){
      float4 zn = *(const float4*)&pz[c*68 + a*4];
      float4 oc = *(const float4*)&Ol[c*64 + b*4];
#pragma unroll
      for(int na=0;na<4;na++){
        float zv = (&zn.x)[na];
        outacc[na*4+0] = fmaf(zv, oc.x, outacc[na*4+0]);
        outacc[na*4+1] = fmaf(zv, oc.y, outacc[na*4+1]);
        outacc[na*4+2] = fmaf(zv, oc.z, outacc[na*4+2]);
        outacc[na*4+3] = fmaf(zv, oc.w, outacc[na*4+3]);
      }
    }
  }
  float oas[4], oat[4];
#pragma unroll
  for(int cb=0;cb<4;cb++){ oas[cb] = out_a[b*4+cb]; oat[cb] = out_a[64 + b*4+cb]; }
#pragma unroll
  for(int na=0;na<4;na++){
    int nl = n0 + a*4 + na;
    float4 o = make_float4(outacc[na*4+0], outacc[na*4+1], outacc[na*4+2], outacc[na*4+3]);
    float sp = o.x*oas[0] + o.y*oas[1] + o.z*oas[2] + o.w*oas[3];
    float st = o.x*oat[0] + o.y*oat[1] + o.z*oat[2] + o.w*oat[3];
#pragma unroll
    for(int msk=1; msk<16; msk<<=1){
      sp += __shfl_xor(sp, msk, 64);
      st += __shfl_xor(st, msk, 64);
    }
    if(nl < cn){
      *(float4*)&h2f[(size_t)(nbase + nl)*64 + b*4] = o;
      if(b == 0){ ps_o[nbase + nl] = sp; pt_o[nbase + nl] = st; }
    }
  }
}

// single-pass output aggregation + log_softmax
__global__ __launch_bounds__(256) void agg_out(const int* __restrict__ offs, const int* __restrict__ tgt_s,
                                               const float* __restrict__ ps_o, const float* __restrict__ pt_o,
                                               const float* __restrict__ q_out, const float* __restrict__ h2f,
                                               const unsigned* __restrict__ mx, float* __restrict__ dout){
  int wid  = (blockIdx.x*blockDim.x + threadIdx.x) >> 6;
  int lane = threadIdx.x & 63;
  if(wid >= NN) return;
  int quad = lane >> 4, l16 = lane & 15;
  int b  = offs[wid];
  int e2 = offs[wid+1];
  float ps = ps_o[wid];
  float B = decf(mx[8]) + decf(mx[32]) + decf(mx[33]);
  float M = (B > 0.f) ? B : 0.01f*B;
  const float4* H4 = (const float4*)h2f;
  float4 num = make_float4(0.f,0.f,0.f,0.f);
  float den = 0.f;
  for(int i=b+quad; i<e2; i+=4){
    int t = tgt_s[i];
    float s = ps + pt_o[t] + q_out[i];
    s = (s > 0.f) ? s : 0.01f*s;
    float w = __expf(s - M);
    den += w;
    float4 hv = H4[(size_t)t*16 + l16];
    num.x += w*hv.x; num.y += w*hv.y; num.z += w*hv.z; num.w += w*hv.w;
  }
  den   += __shfl_xor(den,16,64);   den   += __shfl_xor(den,32,64);
  num.x += __shfl_xor(num.x,16,64); num.x += __shfl_xor(num.x,32,64);
  num.y += __shfl_xor(num.y,16,64); num.y += __shfl_xor(num.y,32,64);
  num.z += __shfl_xor(num.z,16,64); num.z += __shfl_xor(num.z,32,64);
  num.w += __shfl_xor(num.w,16,64); num.w += __shfl_xor(num.w,32,64);
  float inv = (den > 0.f) ? 1.0f/den : 0.f;
  float z[4];
  float mloc = -3.0e38f;
#pragma unroll
  for(int k=0;k<4;k++){
    float hp = ((&num.x)[k]) * inv;
    z[k] = (hp > 0.f) ? hp : expm1f(hp);
    mloc = fmaxf(mloc, z[k]);
  }
#pragma unroll
  for(int msk=1; msk<16; msk<<=1) mloc = fmaxf(mloc, __shfl_xor(mloc,msk,64));
  float ssum = 0.f;
#pragma unroll
  for(int k=0;k<4;k++) ssum += __expf(z[k] - mloc);
#pragma unroll
  for(int msk=1; msk<16; msk<<=1) ssum += __shfl_xor(ssum,msk,64);
  float lse = mloc + logf(ssum);
  if(quad == 0){
    float4 o = make_float4(z[0]-lse, z[1]-lse, z[2]-lse, z[3]-lse);
    ((float4*)dout)[(size_t)wid*16 + l16] = o;
  }
}

extern "C" void kernel_launch(void* const* d_in, const int* in_sizes, int n_in,
                              void* d_out, int out_size, void* d_ws, size_t ws_size,
                              hipStream_t stream) {
  const float* X         = (const float*)d_in[0];
  const float* edge_attr = (const float*)d_in[1];
  const int*   edge_index= (const int*)d_in[2];
  const float* w_node    = (const float*)d_in[4];
  const float* b_node    = (const float*)d_in[5];
  const float* g_node    = (const float*)d_in[6];
  const float* beta_node = (const float*)d_in[7];
  const float* w_edge    = (const float*)d_in[8];
  const float* b_edge    = (const float*)d_in[9];
  const float* g_edge    = (const float*)d_in[10];
  const float* beta_edge = (const float*)d_in[11];
  const float* gat_W     = (const float*)d_in[12];
  const float* gat_a     = (const float*)d_in[13];
  const float* out_W     = (const float*)d_in[14];
  const float* out_a     = (const float*)d_in[15];
  float* dout = (float*)d_out;

  const int* src = edge_index;
  const int* tgt = edge_index + EE;

  char* base = (char*)d_ws;
  size_t off = 0;
  auto take = [&](size_t bytes)->char*{ char* p = base + off; off += (bytes + 31) & ~(size_t)31; return p; };
  int*      counts = (int*)     take((size_t)NN*4);
  int*      cursor = (int*)     take((size_t)NN*4);
  int*      offs   = (int*)     take((size_t)(NN+1)*4);
  int*      bsum   = (int*)     take(256*4);
  int*      bpre   = (int*)     take(256*4);
  unsigned* mx     = (unsigned*)take(64*4);
  float*    ps_o   = (float*)   take((size_t)NN*4);
  float*    pt_o   = (float*)   take((size_t)NN*4);
  float*    cdir   = (float*)   take(1024*4);
  int*      rank   = (int*)     take((size_t)EE*4);
  int*      tgt_s  = (int*)     take((size_t)EE*4);
  float*    ps8    = (float*)   take((size_t)NN*8*4);
  float*    pt8    = (float*)   take((size_t)NN*8*4);
  float*    x      = (float*)   take((size_t)NN*64*4);
  float*    h2f    = (float*)   take((size_t)NN*64*4);
  float*    q8     = (float*)   take((size_t)EE*8*4);
  float*    q_out  = (float*)   take((size_t)EE*4);
  float*    pre    = (float*)   take((size_t)HALF*512*4);
  // total ~125 MB

  const int NBLK_N  = (NN*64 + 255)/256;
  const int NBLK_E  = (EE + 255)/256;
  const int NBLK_S  = (NN + 255)/256;
  const int NBLK_A  = HALF/4;
  const int NBLK_T  = (HALF + 63)/64;

  zero_k   <<<NBLK_S, 256, 0, stream>>>(counts, cursor, mx);
  node_mlp <<<NBLK_N, 256, 0, stream>>>(X, w_node, b_node, g_node, beta_node, x);
  hist_k   <<<NBLK_E, 256, 0, stream>>>(src, counts);
  scan1_k  <<<NBLK_S, 256, 0, stream>>>(counts, bsum);
  scan2_k  <<<1,      256, 0, stream>>>(bsum, bpre, offs);
  scan3_k  <<<NBLK_S, 256, 0, stream>>>(counts, bpre, offs);
  scatter_k<<<NBLK_E, 256, 0, stream>>>(src, tgt, offs, cursor, rank, tgt_s);
  edge_mlp_q<<<NBLK_E,256, 0, stream>>>(rank, edge_attr, w_edge, b_edge, g_edge, beta_edge,
                                        gat_a, out_a, q8, q_out);
  maxq_k   <<<1024,   256, 0, stream>>>(q8, q_out, mx);
  cvec_k   <<<8,       64, 0, stream>>>(gat_W, gat_a, cdir);
  pq_k     <<<NBLK_N, 256, 0, stream>>>(x, cdir, ps8, pt8);
  maxp_k   <<<128,    256, 0, stream>>>(ps8, pt8, mx);

  for(int half=0; half<2; half++){
    int nbase = half*HALF;
    agg_k      <<<NBLK_A, 256, 0, stream>>>(offs, tgt_s, ps8, pt8, q8, x, mx, pre, nbase);
    transform_k<<<NBLK_T, 256, 0, stream>>>(pre, gat_W, out_W, out_a, h2f, ps_o, pt_o, nbase, HALF);
  }

  maxpo_k<<<128, 256, 0, stream>>>(ps_o, pt_o, mx);
  agg_out<<<NBLK_N, 256, 0, stream>>>(offs, tgt_s, ps_o, pt_o, q_out, h2f, mx, dout);
}

// Round 10
// 844.205 us; speedup vs baseline: 2.3617x; 1.1006x over previous
//
#include <hip/hip_runtime.h>

#define NN 50000
#define EE 1000000
#define HALF 25000

__device__ __forceinline__ float wsum(float v){
#pragma unroll
  for(int m=1;m<64;m<<=1) v += __shfl_xor(v,m,64);
  return v;
}
__device__ __forceinline__ unsigned encf(float f){
  unsigned u = __float_as_uint(f);
  return (u & 0x80000000u) ? ~u : (u | 0x80000000u);
}
__device__ __forceinline__ float decf(unsigned u){
  u = (u & 0x80000000u) ? (u & 0x7fffffffu) : ~u;
  return __uint_as_float(u);
}

__global__ __launch_bounds__(256) void zero_k(int* counts, int* cursor, unsigned* mx){
  int i = blockIdx.x*blockDim.x + threadIdx.x;
  if(i < NN){ counts[i] = 0; cursor[i] = 0; }
  if(i < 64) mx[i] = 0u;
}

__global__ __launch_bounds__(64) void cvec_k(const float* __restrict__ gat_W, const float* __restrict__ gat_a,
                                             float* __restrict__ cdir){
  int h = blockIdx.x, k = threadIdx.x;
  const float* W = gat_W + (size_t)h*64*64;
  const float* a = gat_a + (size_t)h*192;
  float cs = 0.f, ct = 0.f;
#pragma unroll
  for(int j=0;j<64;j++){ float wv = W[k*64+j]; cs += wv*a[j]; ct += wv*a[64+j]; }
  cdir[h*64 + k]       = cs;
  cdir[512 + h*64 + k] = ct;
}

// node MLP fused with per-head projections ps8/pt8
__global__ __launch_bounds__(256) void node_mlp(const float* __restrict__ X, const float* __restrict__ w,
                                                const float* __restrict__ b, const float* __restrict__ g,
                                                const float* __restrict__ beta, const float* __restrict__ cdir,
                                                float* __restrict__ x, float* __restrict__ ps8,
                                                float* __restrict__ pt8){
  int wid  = (blockIdx.x*blockDim.x + threadIdx.x) >> 6;
  int lane = threadIdx.x & 63;
  if(wid >= NN) return;
  float acc = b[lane];
#pragma unroll
  for(int k=0;k<16;k++) acc += X[wid*16+k] * w[k*64+lane];
  float mu  = wsum(acc) * (1.0f/64.0f);
  float d   = acc - mu;
  float var = wsum(d*d) * (1.0f/64.0f);
  float y   = d * rsqrtf(var + 1e-5f) * g[lane] + beta[lane];
  float xv  = fmaxf(y, 0.0f);
  x[(size_t)wid*64 + lane] = xv;
#pragma unroll 1
  for(int h=0;h<8;h++){
    float a = wsum(xv * cdir[h*64+lane]);
    float c = wsum(xv * cdir[512 + h*64+lane]);
    if(lane == 0){ ps8[wid*8+h] = a; pt8[wid*8+h] = c; }
  }
}

__global__ __launch_bounds__(256) void hist_k(const int* __restrict__ src, int* __restrict__ counts){
  int e = blockIdx.x*blockDim.x + threadIdx.x;
  if(e < EE){
    int s = src[e];
    if((unsigned)s >= NN) s = 0;
    atomicAdd(&counts[s], 1);
  }
}

__global__ __launch_bounds__(256) void scan1_k(const int* __restrict__ counts, int* __restrict__ bsum){
  int i = blockIdx.x*256 + threadIdx.x;
  int v = (i < NN) ? counts[i] : 0;
  int s = v;
#pragma unroll
  for(int m=1;m<64;m<<=1) s += __shfl_xor(s,m,64);
  __shared__ int sm[4];
  if((threadIdx.x & 63) == 0) sm[threadIdx.x>>6] = s;
  __syncthreads();
  if(threadIdx.x == 0) bsum[blockIdx.x] = sm[0]+sm[1]+sm[2]+sm[3];
}

__global__ __launch_bounds__(256) void scan2_k(const int* __restrict__ bsum, int* __restrict__ bpre,
                                               int* __restrict__ offs){
  const int NB = (NN + 255)/256;
  int t = threadIdx.x;
  __shared__ int sm[256];
  int v = (t < NB) ? bsum[t] : 0;
  sm[t] = v; __syncthreads();
  for(int off=1; off<256; off<<=1){
    int u = (t >= off) ? sm[t-off] : 0;
    __syncthreads();
    sm[t] += u;
    __syncthreads();
  }
  if(t < NB) bpre[t] = sm[t] - v;
  if(t == 0) offs[NN] = EE;
}

__global__ __launch_bounds__(256) void scan3_k(const int* __restrict__ counts, const int* __restrict__ bpre,
                                               int* __restrict__ offs){
  int i = blockIdx.x*256 + threadIdx.x;
  int t = threadIdx.x;
  __shared__ int sm[256];
  int v = (i < NN) ? counts[i] : 0;
  sm[t] = v; __syncthreads();
  for(int off=1; off<256; off<<=1){
    int u = (t >= off) ? sm[t-off] : 0;
    __syncthreads();
    sm[t] += u;
    __syncthreads();
  }
  if(i < NN) offs[i] = bpre[blockIdx.x] + sm[t] - v;
}

// rank[e]=CSR pos; tgt_s/src_s in CSR order
__global__ __launch_bounds__(256) void scatter_k(const int* __restrict__ src, const int* __restrict__ tgt,
                                                 const int* __restrict__ offs, int* __restrict__ cursor,
                                                 int* __restrict__ rank, int* __restrict__ tgt_s,
                                                 int* __restrict__ src_s){
  int e = blockIdx.x*blockDim.x + threadIdx.x;
  if(e < EE){
    int s = src[e];
    if((unsigned)s >= NN) s = 0;
    int pos = offs[s] + atomicAdd(&cursor[s], 1);
    rank[e] = pos;
    int t = tgt[e];
    if((unsigned)t >= NN) t = 0;
    tgt_s[pos] = t;
    src_s[pos] = s;
  }
}

// edge MLP v2: all weights staged in LDS (broadcast ds_reads, no per-lane VMEM weight traffic)
__global__ __launch_bounds__(256) void edge_mlp_q(const int* __restrict__ rank, const float* __restrict__ ea,
                                                  const float* __restrict__ w, const float* __restrict__ b,
                                                  const float* __restrict__ g, const float* __restrict__ beta,
                                                  const float* __restrict__ gat_a, const float* __restrict__ out_a,
                                                  float* __restrict__ q8, float* __restrict__ q_out){
  __shared__ float wle[512];      // wle[j*8+k] = w[k*64+j]
  __shared__ float ble[64], gle[64], bbe[64];
  __shared__ float ale[64*12];    // ale[j*12+r], r=0..7 gat_a, r=8 out_a
  int tid = threadIdx.x;
  for(int idx=tid; idx<512; idx+=256){ int j=idx>>3, k=idx&7; wle[idx] = w[k*64+j]; }
  if(tid < 64){
    ble[tid] = b[tid]; gle[tid] = g[tid]; bbe[tid] = beta[tid];
#pragma unroll
    for(int r=0;r<8;r++) ale[tid*12+r] = gat_a[r*192 + 128 + tid];
    ale[tid*12+8] = out_a[128 + tid];
  }
  __syncthreads();
  int e = blockIdx.x*blockDim.x + tid;
  if(e >= EE) return;
  float4 ia = ((const float4*)ea)[(size_t)e*2];
  float4 ib = ((const float4*)ea)[(size_t)e*2+1];
  float y[64];
#pragma unroll
  for(int j=0;j<64;j++){
    float4 w0 = *(const float4*)&wle[j*8];
    float4 w1 = *(const float4*)&wle[j*8+4];
    float acc = ble[j];
    acc = fmaf(ia.x,w0.x, fmaf(ia.y,w0.y, fmaf(ia.z,w0.z, fmaf(ia.w,w0.w, acc))));
    acc = fmaf(ib.x,w1.x, fmaf(ib.y,w1.y, fmaf(ib.z,w1.z, fmaf(ib.w,w1.w, acc))));
    y[j] = acc;
  }
  float mu = 0.f;
#pragma unroll
  for(int j=0;j<64;j++) mu += y[j];
  mu *= (1.0f/64.0f);
  float var = 0.f;
#pragma unroll
  for(int j=0;j<64;j++){ float d = y[j]-mu; var += d*d; }
  var *= (1.0f/64.0f);
  float inv = rsqrtf(var + 1e-5f);
#pragma unroll
  for(int j=0;j<64;j++) y[j] = fmaxf((y[j]-mu)*inv*gle[j] + bbe[j], 0.0f);
  float qv[9];
#pragma unroll
  for(int r=0;r<9;r++) qv[r] = 0.f;
#pragma unroll
  for(int j=0;j<64;j++){
    float4 a0 = *(const float4*)&ale[j*12];
    float4 a1 = *(const float4*)&ale[j*12+4];
    float a8  = ale[j*12+8];
    float yj = y[j];
    qv[0]=fmaf(yj,a0.x,qv[0]); qv[1]=fmaf(yj,a0.y,qv[1]); qv[2]=fmaf(yj,a0.z,qv[2]); qv[3]=fmaf(yj,a0.w,qv[3]);
    qv[4]=fmaf(yj,a1.x,qv[4]); qv[5]=fmaf(yj,a1.y,qv[5]); qv[6]=fmaf(yj,a1.z,qv[6]); qv[7]=fmaf(yj,a1.w,qv[7]);
    qv[8]=fmaf(yj,a8 ,qv[8]);
  }
  int r = rank[e];
  ((float4*)q8)[(size_t)r*2]   = make_float4(qv[0],qv[1],qv[2],qv[3]);
  ((float4*)q8)[(size_t)r*2+1] = make_float4(qv[4],qv[5],qv[6],qv[7]);
  q_out[r] = qv[8];
}

__global__ __launch_bounds__(256) void maxq_k(const float* __restrict__ q8, const float* __restrict__ q_out,
                                              unsigned* __restrict__ mx){
  float m[9];
#pragma unroll
  for(int r=0;r<9;r++) m[r] = -3.0e38f;
  for(int i = blockIdx.x*256 + threadIdx.x; i < EE; i += gridDim.x*256){
    float4 a = ((const float4*)q8)[(size_t)i*2];
    float4 c = ((const float4*)q8)[(size_t)i*2+1];
    m[0]=fmaxf(m[0],a.x); m[1]=fmaxf(m[1],a.y); m[2]=fmaxf(m[2],a.z); m[3]=fmaxf(m[3],a.w);
    m[4]=fmaxf(m[4],c.x); m[5]=fmaxf(m[5],c.y); m[6]=fmaxf(m[6],c.z); m[7]=fmaxf(m[7],c.w);
    m[8]=fmaxf(m[8], q_out[i]);
  }
#pragma unroll
  for(int r=0;r<9;r++)
#pragma unroll
    for(int msk=1;msk<64;msk<<=1) m[r] = fmaxf(m[r], __shfl_xor(m[r],msk,64));
  __shared__ float sm[4][9];
  int wv = threadIdx.x>>6, lane = threadIdx.x&63;
  if(lane == 0){
#pragma unroll
    for(int r=0;r<9;r++) sm[wv][r] = m[r];
  }
  __syncthreads();
  if(threadIdx.x < 9){
    int r = threadIdx.x;
    float v = fmaxf(fmaxf(sm[0][r],sm[1][r]), fmaxf(sm[2][r],sm[3][r]));
    atomicMax(&mx[r], encf(v));
  }
}

__global__ __launch_bounds__(256) void maxp_k(const float* __restrict__ ps8, const float* __restrict__ pt8,
                                              unsigned* __restrict__ mx){
  float m[16];
#pragma unroll
  for(int r=0;r<16;r++) m[r] = -3.0e38f;
  for(int i = blockIdx.x*256 + threadIdx.x; i < NN; i += gridDim.x*256){
    float4 a = ((const float4*)ps8)[(size_t)i*2];
    float4 c = ((const float4*)ps8)[(size_t)i*2+1];
    float4 d = ((const float4*)pt8)[(size_t)i*2];
    float4 e = ((const float4*)pt8)[(size_t)i*2+1];
    m[0]=fmaxf(m[0],a.x); m[1]=fmaxf(m[1],a.y); m[2]=fmaxf(m[2],a.z); m[3]=fmaxf(m[3],a.w);
    m[4]=fmaxf(m[4],c.x); m[5]=fmaxf(m[5],c.y); m[6]=fmaxf(m[6],c.z); m[7]=fmaxf(m[7],c.w);
    m[8]=fmaxf(m[8],d.x); m[9]=fmaxf(m[9],d.y); m[10]=fmaxf(m[10],d.z); m[11]=fmaxf(m[11],d.w);
    m[12]=fmaxf(m[12],e.x); m[13]=fmaxf(m[13],e.y); m[14]=fmaxf(m[14],e.z); m[15]=fmaxf(m[15],e.w);
  }
#pragma unroll
  for(int r=0;r<16;r++)
#pragma unroll
    for(int msk=1;msk<64;msk<<=1) m[r] = fmaxf(m[r], __shfl_xor(m[r],msk,64));
  __shared__ float sm[4][16];
  int wv = threadIdx.x>>6, lane = threadIdx.x&63;
  if(lane == 0){
#pragma unroll
    for(int r=0;r<16;r++) sm[wv][r] = m[r];
  }
  __syncthreads();
  if(threadIdx.x < 16){
    int r = threadIdx.x;
    float v = fmaxf(fmaxf(sm[0][r],sm[1][r]), fmaxf(sm[2][r],sm[3][r]));
    atomicMax(&mx[16+r], encf(v));
  }
}

__global__ __launch_bounds__(256) void maxpo_k(const float* __restrict__ ps_o, const float* __restrict__ pt_o,
                                               unsigned* __restrict__ mx){
  float m0 = -3.0e38f, m1 = -3.0e38f;
  for(int i = blockIdx.x*256 + threadIdx.x; i < NN; i += gridDim.x*256){
    m0 = fmaxf(m0, ps_o[i]); m1 = fmaxf(m1, pt_o[i]);
  }
#pragma unroll
  for(int msk=1;msk<64;msk<<=1){ m0=fmaxf(m0,__shfl_xor(m0,msk,64)); m1=fmaxf(m1,__shfl_xor(m1,msk,64)); }
  __shared__ float sm[4][2];
  int wv = threadIdx.x>>6, lane = threadIdx.x&63;
  if(lane == 0){ sm[wv][0]=m0; sm[wv][1]=m1; }
  __syncthreads();
  if(threadIdx.x < 2){
    int r = threadIdx.x;
    float v = fmaxf(fmaxf(sm[0][r],sm[1][r]), fmaxf(sm[2][r],sm[3][r]));
    atomicMax(&mx[32+r], encf(v));
  }
}

// edge-parallel exp-weight precompute (in-place on q8): w8 = exp(lrelu(ps+pt+q) - M)
__global__ __launch_bounds__(256) void score_k(const int* __restrict__ src_s, const int* __restrict__ tgt_s,
                                               const float* __restrict__ ps8, const float* __restrict__ pt8,
                                               const unsigned* __restrict__ mx, float* __restrict__ q8){
  int i = blockIdx.x*256 + threadIdx.x;
  if(i >= EE) return;
  int s = src_s[i], t = tgt_s[i];
  float4 qa = ((const float4*)q8)[(size_t)i*2];
  float4 qb = ((const float4*)q8)[(size_t)i*2+1];
  float4 sa = ((const float4*)ps8)[(size_t)s*2];
  float4 sb = ((const float4*)ps8)[(size_t)s*2+1];
  float4 ta = ((const float4*)pt8)[(size_t)t*2];
  float4 tb = ((const float4*)pt8)[(size_t)t*2+1];
  float sv[8] = {qa.x+sa.x+ta.x, qa.y+sa.y+ta.y, qa.z+sa.z+ta.z, qa.w+sa.w+ta.w,
                 qb.x+sb.x+tb.x, qb.y+sb.y+tb.y, qb.z+sb.z+tb.z, qb.w+sb.w+tb.w};
  float wv[8];
#pragma unroll
  for(int h=0;h<8;h++){
    float B = decf(mx[h]) + decf(mx[16+h]) + decf(mx[24+h]);
    float M = (B > 0.f) ? B : 0.01f*B;
    float x = sv[h];
    x = (x > 0.f) ? x : 0.01f*x;
    wv[h] = __expf(x - M);
  }
  ((float4*)q8)[(size_t)i*2]   = make_float4(wv[0],wv[1],wv[2],wv[3]);
  ((float4*)q8)[(size_t)i*2+1] = make_float4(wv[4],wv[5],wv[6],wv[7]);
}

// output-layer exp-weights (in-place on q_out)
__global__ __launch_bounds__(256) void score_out_k(const int* __restrict__ src_s, const int* __restrict__ tgt_s,
                                                   const float* __restrict__ ps_o, const float* __restrict__ pt_o,
                                                   const unsigned* __restrict__ mx, float* __restrict__ q_out){
  int i = blockIdx.x*256 + threadIdx.x;
  if(i >= EE) return;
  float B = decf(mx[8]) + decf(mx[32]) + decf(mx[33]);
  float M = (B > 0.f) ? B : 0.01f*B;
  float x = ps_o[src_s[i]] + pt_o[tgt_s[i]] + q_out[i];
  x = (x > 0.f) ? x : 0.01f*x;
  q_out[i] = __expf(x - M);
}

// aggregation: pure weighted gather (weights precomputed)
__global__ __launch_bounds__(256) void agg_k(const int* __restrict__ offs, const int* __restrict__ tgt_s,
    const float* __restrict__ w8, const float* __restrict__ x, float* __restrict__ pre, int nbase){
  int wid  = nbase + ((blockIdx.x*blockDim.x + threadIdx.x) >> 6);
  int lane = threadIdx.x & 63;
  int quad = lane >> 4, l16 = lane & 15;
  int b  = offs[wid];
  int e2 = offs[wid+1];
  float  den[8];
  float4 num[8];
#pragma unroll
  for(int h=0;h<8;h++){ den[h] = 0.f; num[h] = make_float4(0.f,0.f,0.f,0.f); }
  const float4* X4 = (const float4*)x;
  for(int i=b+quad; i<e2; i+=4){
    int t = tgt_s[i];
    float4 wa = ((const float4*)w8)[(size_t)i*2];
    float4 wb = ((const float4*)w8)[(size_t)i*2+1];
    float4 xv = X4[(size_t)t*16 + l16];
    float wv[8] = {wa.x,wa.y,wa.z,wa.w, wb.x,wb.y,wb.z,wb.w};
#pragma unroll
    for(int h=0;h<8;h++){
      den[h]   += wv[h];
      num[h].x = fmaf(wv[h],xv.x,num[h].x); num[h].y = fmaf(wv[h],xv.y,num[h].y);
      num[h].z = fmaf(wv[h],xv.z,num[h].z); num[h].w = fmaf(wv[h],xv.w,num[h].w);
    }
  }
#pragma unroll
  for(int h=0;h<8;h++){
    den[h]   += __shfl_xor(den[h],16,64);   den[h]   += __shfl_xor(den[h],32,64);
    num[h].x += __shfl_xor(num[h].x,16,64); num[h].x += __shfl_xor(num[h].x,32,64);
    num[h].y += __shfl_xor(num[h].y,16,64); num[h].y += __shfl_xor(num[h].y,32,64);
    num[h].z += __shfl_xor(num[h].z,16,64); num[h].z += __shfl_xor(num[h].z,32,64);
    num[h].w += __shfl_xor(num[h].w,16,64); num[h].w += __shfl_xor(num[h].w,32,64);
  }
  float* dst = pre + (size_t)(wid - nbase)*512;
#pragma unroll
  for(int k=0;k<2;k++){
    int h = 2*quad + k;
    float invd = (den[h] > 0.f) ? 1.0f/den[h] : 0.f;
    float4 o = make_float4(num[h].x*invd, num[h].y*invd, num[h].z*invd, num[h].w*invd);
    ((float4*)(dst + h*64))[l16] = o;
  }
}

// transform v3 (validated in R8): LDS-tiled GEMM, epilogue h2f + ps_o/pt_o
__global__ __launch_bounds__(256) void transform_k(const float* __restrict__ pre,
                                                   const float* __restrict__ gat_W,
                                                   const float* __restrict__ outW,
                                                   const float* __restrict__ out_a,
                                                   float* __restrict__ h2f,
                                                   float* __restrict__ ps_o,
                                                   float* __restrict__ pt_o,
                                                   int nbase, int cn){
  __shared__ float pz[64*68];
  __shared__ float Wl[4096];
  __shared__ float Ol[4096];
  int tid = threadIdx.x;
  int n0  = blockIdx.x * 64;
  int a   = tid >> 4;
  int b   = tid & 15;
  float outacc[16];
#pragma unroll
  for(int i=0;i<16;i++) outacc[i] = 0.f;
#pragma unroll 1
  for(int h=0; h<8; h++){
    __syncthreads();
#pragma unroll 1
    for(int r=0;r<16;r++){
      int flat = r*256 + tid;
      int n = flat >> 6, j = flat & 63;
      int gn = n0 + n;
      pz[j*68 + n] = (gn < cn) ? pre[(size_t)gn*512 + h*64 + j] : 0.f;
      Wl[flat] = gat_W[(size_t)h*4096 + flat];
      Ol[flat] = outW [(size_t)h*4096 + flat];
    }
    __syncthreads();
    float v[16];
#pragma unroll
    for(int i=0;i<16;i++) v[i] = 0.f;
#pragma unroll 4
    for(int j=0;j<64;j++){
      float4 pn = *(const float4*)&pz[j*68 + a*4];
      float4 wc = *(const float4*)&Wl[j*64 + b*4];
#pragma unroll
      for(int na=0;na<4;na++){
        float pv = (&pn.x)[na];
        v[na*4+0] = fmaf(pv, wc.x, v[na*4+0]);
        v[na*4+1] = fmaf(pv, wc.y, v[na*4+1]);
        v[na*4+2] = fmaf(pv, wc.z, v[na*4+2]);
        v[na*4+3] = fmaf(pv, wc.w, v[na*4+3]);
      }
    }
    __syncthreads();
#pragma unroll
    for(int cb=0;cb<4;cb++){
      float4 z4;
#pragma unroll
      for(int na=0;na<4;na++){
        float z  = (v[na*4+cb] > 0.f) ? v[na*4+cb] : expm1f(v[na*4+cb]);
        float z2 = (z > 0.f) ? z : expm1f(z);
        (&z4.x)[na] = z2;
      }
      *(float4*)&pz[(b*4+cb)*68 + a*4] = z4;
    }
    __syncthreads();
#pragma unroll 4
    for(int c=0;c<64;c++){
      float4 zn = *(const float4*)&pz[c*68 + a*4];
      float4 oc = *(const float4*)&Ol[c*64 + b*4];
#pragma unroll
      for(int na=0;na<4;na++){
        float zv = (&zn.x)[na];
        outacc[na*4+0] = fmaf(zv, oc.x, outacc[na*4+0]);
        outacc[na*4+1] = fmaf(zv, oc.y, outacc[na*4+1]);
        outacc[na*4+2] = fmaf(zv, oc.z, outacc[na*4+2]);
        outacc[na*4+3] = fmaf(zv, oc.w, outacc[na*4+3]);
      }
    }
  }
  float oas[4], oat[4];
#pragma unroll
  for(int cb=0;cb<4;cb++){ oas[cb] = out_a[b*4+cb]; oat[cb] = out_a[64 + b*4+cb]; }
#pragma unroll
  for(int na=0;na<4;na++){
    int nl = n0 + a*4 + na;
    float4 o = make_float4(outacc[na*4+0], outacc[na*4+1], outacc[na*4+2], outacc[na*4+3]);
    float sp = o.x*oas[0] + o.y*oas[1] + o.z*oas[2] + o.w*oas[3];
    float st = o.x*oat[0] + o.y*oat[1] + o.z*oat[2] + o.w*oat[3];
#pragma unroll
    for(int msk=1; msk<16; msk<<=1){
      sp += __shfl_xor(sp, msk, 64);
      st += __shfl_xor(st, msk, 64);
    }
    if(nl < cn){
      *(float4*)&h2f[(size_t)(nbase + nl)*64 + b*4] = o;
      if(b == 0){ ps_o[nbase + nl] = sp; pt_o[nbase + nl] = st; }
    }
  }
}

// output aggregation (weights precomputed) + log_softmax
__global__ __launch_bounds__(256) void agg_out(const int* __restrict__ offs, const int* __restrict__ tgt_s,
                                               const float* __restrict__ w_out, const float* __restrict__ h2f,
                                               float* __restrict__ dout){
  int wid  = (blockIdx.x*blockDim.x + threadIdx.x) >> 6;
  int lane = threadIdx.x & 63;
  if(wid >= NN) return;
  int quad = lane >> 4, l16 = lane & 15;
  int b  = offs[wid];
  int e2 = offs[wid+1];
  const float4* H4 = (const float4*)h2f;
  float4 num = make_float4(0.f,0.f,0.f,0.f);
  float den = 0.f;
  for(int i=b+quad; i<e2; i+=4){
    int t = tgt_s[i];
    float w = w_out[i];
    float4 hv = H4[(size_t)t*16 + l16];
    den += w;
    num.x = fmaf(w,hv.x,num.x); num.y = fmaf(w,hv.y,num.y);
    num.z = fmaf(w,hv.z,num.z); num.w = fmaf(w,hv.w,num.w);
  }
  den   += __shfl_xor(den,16,64);   den   += __shfl_xor(den,32,64);
  num.x += __shfl_xor(num.x,16,64); num.x += __shfl_xor(num.x,32,64);
  num.y += __shfl_xor(num.y,16,64); num.y += __shfl_xor(num.y,32,64);
  num.z += __shfl_xor(num.z,16,64); num.z += __shfl_xor(num.z,32,64);
  num.w += __shfl_xor(num.w,16,64); num.w += __shfl_xor(num.w,32,64);
  float inv = (den > 0.f) ? 1.0f/den : 0.f;
  float z[4];
  float mloc = -3.0e38f;
#pragma unroll
  for(int k=0;k<4;k++){
    float hp = ((&num.x)[k]) * inv;
    z[k] = (hp > 0.f) ? hp : expm1f(hp);
    mloc = fmaxf(mloc, z[k]);
  }
#pragma unroll
  for(int msk=1; msk<16; msk<<=1) mloc = fmaxf(mloc, __shfl_xor(mloc,msk,64));
  float ssum = 0.f;
#pragma unroll
  for(int k=0;k<4;k++) ssum += __expf(z[k] - mloc);
#pragma unroll
  for(int msk=1; msk<16; msk<<=1) ssum += __shfl_xor(ssum,msk,64);
  float lse = mloc + logf(ssum);
  if(quad == 0){
    float4 o = make_float4(z[0]-lse, z[1]-lse, z[2]-lse, z[3]-lse);
    ((float4*)dout)[(size_t)wid*16 + l16] = o;
  }
}

extern "C" void kernel_launch(void* const* d_in, const int* in_sizes, int n_in,
                              void* d_out, int out_size, void* d_ws, size_t ws_size,
                              hipStream_t stream) {
  const float* X         = (const float*)d_in[0];
  const float* edge_attr = (const float*)d_in[1];
  const int*   edge_index= (const int*)d_in[2];
  const float* w_node    = (const float*)d_in[4];
  const float* b_node    = (const float*)d_in[5];
  const float* g_node    = (const float*)d_in[6];
  const float* beta_node = (const float*)d_in[7];
  const float* w_edge    = (const float*)d_in[8];
  const float* b_edge    = (const float*)d_in[9];
  const float* g_edge    = (const float*)d_in[10];
  const float* beta_edge = (const float*)d_in[11];
  const float* gat_W     = (const float*)d_in[12];
  const float* gat_a     = (const float*)d_in[13];
  const float* out_W     = (const float*)d_in[14];
  const float* out_a     = (const float*)d_in[15];
  float* dout = (float*)d_out;

  const int* src = edge_index;
  const int* tgt = edge_index + EE;

  char* base = (char*)d_ws;
  size_t off = 0;
  auto take = [&](size_t bytes)->char*{ char* p = base + off; off += (bytes + 31) & ~(size_t)31; return p; };
  int*      counts = (int*)     take((size_t)NN*4);
  int*      cursor = (int*)     take((size_t)NN*4);
  int*      offs   = (int*)     take((size_t)(NN+1)*4);
  int*      bsum   = (int*)     take(256*4);
  int*      bpre   = (int*)     take(256*4);
  unsigned* mx     = (unsigned*)take(64*4);
  float*    ps_o   = (float*)   take((size_t)NN*4);
  float*    pt_o   = (float*)   take((size_t)NN*4);
  float*    cdir   = (float*)   take(1024*4);
  int*      rank   = (int*)     take((size_t)EE*4);
  int*      tgt_s  = (int*)     take((size_t)EE*4);
  int*      src_s  = (int*)     take((size_t)EE*4);
  float*    ps8    = (float*)   take((size_t)NN*8*4);
  float*    pt8    = (float*)   take((size_t)NN*8*4);
  float*    x      = (float*)   take((size_t)NN*64*4);
  float*    h2f    = (float*)   take((size_t)NN*64*4);
  float*    q8     = (float*)   take((size_t)EE*8*4);   // becomes w8 after score_k
  float*    q_out  = (float*)   take((size_t)EE*4);     // becomes w_out after score_out_k
  float*    pre    = (float*)   take((size_t)HALF*512*4);
  // total ~129 MB

  const int NBLK_N  = (NN*64 + 255)/256;
  const int NBLK_E  = (EE + 255)/256;
  const int NBLK_S  = (NN + 255)/256;
  const int NBLK_A  = HALF/4;
  const int NBLK_T  = (HALF + 63)/64;

  zero_k   <<<NBLK_S, 256, 0, stream>>>(counts, cursor, mx);
  cvec_k   <<<8,       64, 0, stream>>>(gat_W, gat_a, cdir);
  node_mlp <<<NBLK_N, 256, 0, stream>>>(X, w_node, b_node, g_node, beta_node, cdir, x, ps8, pt8);
  hist_k   <<<NBLK_E, 256, 0, stream>>>(src, counts);
  scan1_k  <<<NBLK_S, 256, 0, stream>>>(counts, bsum);
  scan2_k  <<<1,      256, 0, stream>>>(bsum, bpre, offs);
  scan3_k  <<<NBLK_S, 256, 0, stream>>>(counts, bpre, offs);
  scatter_k<<<NBLK_E, 256, 0, stream>>>(src, tgt, offs, cursor, rank, tgt_s, src_s);
  edge_mlp_q<<<NBLK_E,256, 0, stream>>>(rank, edge_attr, w_edge, b_edge, g_edge, beta_edge,
                                        gat_a, out_a, q8, q_out);
  maxq_k   <<<1024,   256, 0, stream>>>(q8, q_out, mx);
  maxp_k   <<<128,    256, 0, stream>>>(ps8, pt8, mx);
  score_k  <<<NBLK_E, 256, 0, stream>>>(src_s, tgt_s, ps8, pt8, mx, q8);

  for(int half=0; half<2; half++){
    int nbase = half*HALF;
    agg_k      <<<NBLK_A, 256, 0, stream>>>(offs, tgt_s, q8, x, pre, nbase);
    transform_k<<<NBLK_T, 256, 0, stream>>>(pre, gat_W, out_W, out_a, h2f, ps_o, pt_o, nbase, HALF);
  }

  maxpo_k    <<<128,  256, 0, stream>>>(ps_o, pt_o, mx);
  score_out_k<<<NBLK_E,256, 0, stream>>>(src_s, tgt_s, ps_o, pt_o, mx, q_out);
  agg_out    <<<NBLK_N,256, 0, stream>>>(offs, tgt_s, q_out, h2f, dout);
}